// Round 1
// baseline (909.839 us; speedup 1.0000x reference)
//
#include <hip/hip_runtime.h>
#include <cstddef>

// Shapes: N=32, C=256, C8=32, H=W=56
#define NB 32
#define HH 56
#define WW 56

// ---------------- weight fusion kernels ----------------
// W34[ci][k1][k2] = sum_co w3[co,ci,k1] * w4[co,k2]   (32*3*3 = 288)
__global__ void fuse_w34(const float* __restrict__ w3, const float* __restrict__ w4,
                         float* __restrict__ W34) {
    int idx = blockIdx.x * blockDim.x + threadIdx.x;
    if (idx >= 288) return;
    int ci = idx / 9, k1 = (idx / 3) % 3, k2 = idx % 3;
    float s = 0.f;
    for (int co = 0; co < 256; ++co)
        s += w3[(co * 32 + ci) * 3 + k1] * w4[co * 3 + k2];
    W34[idx] = s;
}

// W1215[o][ci][k][j] = sum_m w15[o, 3m+k] * w12[m,ci,j]   (256*32*3*7 = 172032)
__global__ void fuse_w1215(const float* __restrict__ w15, const float* __restrict__ w12,
                           float* __restrict__ Wf) {
    int idx = blockIdx.x * blockDim.x + threadIdx.x;
    if (idx >= 256 * 32 * 21) return;
    int j = idx % 7, k = (idx / 7) % 3, ci = (idx / 21) % 32, o = idx / 672;
    float s = 0.f;
    for (int m = 0; m < 256; ++m)
        s += w15[o * 768 + m * 3 + k] * w12[(m * 32 + ci) * 7 + j];
    Wf[idx] = s;
}

// ---------------- t1: conv 256->32, 3 w-taps dil 3 ----------------
// grid 448 (= N*H/4), block 256: 4 rows per block, per row-unit 64 thr = 8 cog(x4 co) * 8 pxg(x7 px)
__global__ __launch_bounds__(256) void k_t1(const float* __restrict__ x,
                                            const float* __restrict__ w1,
                                            float* __restrict__ t1) {
    int by = blockIdx.x;
    int n = by / 14;
    int y = (by % 14) * 4 + (threadIdx.x >> 6);
    int u = threadIdx.x & 63;
    int co0 = (u >> 3) * 4;
    int px0 = (u & 7) * 7;
    float acc[4][7] = {};
    for (int ci = 0; ci < 256; ++ci) {
        const float* xr = x + ((size_t)(n * 256 + ci) * 56 + y) * 56;
        float seg[13];
#pragma unroll
        for (int t = 0; t < 13; ++t) {
            int p = px0 - 3 + t;
            seg[t] = (p >= 0 && p < 56) ? xr[p] : 0.f;
        }
#pragma unroll
        for (int k = 0; k < 3; ++k) {
            float wv[4];
#pragma unroll
            for (int j = 0; j < 4; ++j) wv[j] = w1[(co0 + j) * 768 + ci * 3 + k];
#pragma unroll
            for (int j = 0; j < 4; ++j)
#pragma unroll
                for (int p = 0; p < 7; ++p)
                    acc[j][p] += seg[p + 3 * k] * wv[j];
        }
    }
    for (int j = 0; j < 4; ++j)
        for (int p = 0; p < 7; ++p)
            t1[((size_t)(n * 32 + co0 + j) * 56 + y) * 56 + px0 + p] = acc[j][p];
}

// ---------------- t4: 32ch, 3x3 taps dil (2,3), via W34 ----------------
__global__ void k_t4(const float* __restrict__ t1, const float* __restrict__ W34,
                     float* __restrict__ t4) {
    int by = blockIdx.x;  // N*H
    int n = by / 56, y = by % 56;
    int px = threadIdx.x;
    if (px >= 56) return;
    float acc = 0.f;
    for (int ci = 0; ci < 32; ++ci) {
#pragma unroll
        for (int k1 = 0; k1 < 3; ++k1) {
            int yy = y + 2 * k1 - 2;
            if (yy < 0 || yy >= 56) continue;
            const float* r = t1 + ((size_t)(n * 32 + ci) * 56 + yy) * 56;
#pragma unroll
            for (int k2 = 0; k2 < 3; ++k2) {
                int xx = px + 3 * k2 - 3;
                if (xx >= 0 && xx < 56)
                    acc += r[xx] * W34[ci * 9 + k1 * 3 + k2];
            }
        }
    }
    t4[(size_t)(n * 56 + y) * 56 + px] = acc;
}

// ---------------- t5: depthwise 3 h-taps dil 3, input scaled by p2w ----------------
__global__ void k_t5(const float* __restrict__ t1, const float* __restrict__ p2w,
                     const float* __restrict__ w5, float* __restrict__ t5) {
    int idx = blockIdx.x * blockDim.x + threadIdx.x;  // float4 granules
    if (idx >= 802816) return;
    int xq = idx % 14;
    int y = (idx / 14) % 56;
    int g = (idx / (14 * 56)) % 32;
    int n = idx / (14 * 56 * 32);
    float sx = 0.f, sy = 0.f, sz = 0.f, sw = 0.f;
    float scale = p2w[g];
#pragma unroll
    for (int k = 0; k < 3; ++k) {
        int yy = y + 3 * k - 3;
        if (yy < 0 || yy >= 56) continue;
        float w = w5[g * 3 + k] * scale;
        const float4 v = *(const float4*)(t1 + ((size_t)(n * 32 + g) * 56 + yy) * 56 + xq * 4);
        sx += v.x * w; sy += v.y * w; sz += v.z * w; sw += v.w * w;
    }
    float4 s = {sx, sy, sz, sw};
    *(float4*)(t5 + (size_t)idx * 4) = s;
}

// ---------------- pool: t4 -> t11 (max-grid, relu, window-sum /21) ----------------
__global__ void k_pool(const float* __restrict__ t4, float* __restrict__ t11) {
    int by = blockIdx.x;
    int n = by / 56, y = by % 56;
    int px = threadIdx.x;
    if (px >= 56) return;
    float s = 0.f;
    for (int j = 0; j < 7; ++j) {
        int xx = px + 3 * j - 9;
        bool xin = (xx >= 0 && xx < 56);
        for (int dy = -1; dy <= 1; ++dy) {
            int yc = y + dy;
            if (yc < 0 || yc >= 56) continue;  // p9 zero-pad: relu(0)=0 contribution
            float m = -3.4e38f;
            for (int i = 0; i < 7; ++i) {
                int yy = yc + 3 * i - 9;
                float v = (xin && yy >= 0 && yy < 56) ? t4[(size_t)(n * 56 + yy) * 56 + xx] : 0.f;
                m = fmaxf(m, v);
            }
            s += fmaxf(m, 0.f);
        }
    }
    t11[(size_t)(n * 56 + y) * 56 + px] = s * (1.f / 21.f);
}

// ---------------- t14: 3x3 conv on t11 ----------------
__global__ void k_t14(const float* __restrict__ t11, const float* __restrict__ w14,
                      float* __restrict__ t14) {
    int by = blockIdx.x;
    int n = by / 56, y = by % 56;
    int px = threadIdx.x;
    if (px >= 56) return;
    float s = 0.f;
#pragma unroll
    for (int dy = 0; dy < 3; ++dy) {
        int yy = y + dy - 1;
        if (yy < 0 || yy >= 56) continue;
#pragma unroll
        for (int dx = 0; dx < 3; ++dx) {
            int xx = px + dx - 1;
            if (xx < 0 || xx >= 56) continue;
            s += t11[(size_t)(n * 56 + yy) * 56 + xx] * w14[dy * 3 + dx];
        }
    }
    t14[(size_t)(n * 56 + y) * 56 + px] = s;
}

// ---------------- t8: conv 32->32, 7 w-taps dil 2 ----------------
__global__ __launch_bounds__(256) void k_t8(const float* __restrict__ t5,
                                            const float* __restrict__ w8,
                                            float* __restrict__ t8) {
    int by = blockIdx.x;  // 448
    int n = by / 14;
    int y = (by % 14) * 4 + (threadIdx.x >> 6);
    int u = threadIdx.x & 63;
    int co0 = (u >> 3) * 4;
    int px0 = (u & 7) * 7;
    float acc[4][7] = {};
    for (int ci = 0; ci < 32; ++ci) {
        const float* r = t5 + ((size_t)(n * 32 + ci) * 56 + y) * 56;
        float seg[19];
#pragma unroll
        for (int t = 0; t < 19; ++t) {
            int p = px0 - 6 + t;
            seg[t] = (p >= 0 && p < 56) ? r[p] : 0.f;
        }
#pragma unroll
        for (int j = 0; j < 7; ++j) {
            float wv[4];
#pragma unroll
            for (int q = 0; q < 4; ++q) wv[q] = w8[(co0 + q) * 224 + ci * 7 + j];
#pragma unroll
            for (int q = 0; q < 4; ++q)
#pragma unroll
                for (int p = 0; p < 7; ++p)
                    acc[q][p] += seg[p + 2 * j] * wv[q];
        }
    }
    for (int q = 0; q < 4; ++q)
        for (int p = 0; p < 7; ++p)
            t8[((size_t)(n * 32 + co0 + q) * 56 + y) * 56 + px0 + p] = acc[q][p];
}

// ---------------- big fused kernel: t8 -> t15(row, via W1215) -> t16 + t14 -> out ----------------
// grid N*H = 1792, block 256: 32 cog(x8 co) * 8 pxg(x7 px)
__global__ __launch_bounds__(256) void k_t15_out(const float* __restrict__ t8,
                                                 const float* __restrict__ Wf,
                                                 const float* __restrict__ w16,
                                                 const float* __restrict__ t14,
                                                 float* __restrict__ out) {
    __shared__ float row[256][57];
    int by = blockIdx.x;
    int n = by / 56, y = by % 56;
    int co0 = (threadIdx.x >> 3) * 8;
    int px0 = (threadIdx.x & 7) * 7;
    float acc[8][7] = {};
    for (int ci = 0; ci < 32; ++ci) {
#pragma unroll
        for (int dy = 0; dy < 3; ++dy) {
            int yy = y + 2 * dy - 2;
            if (yy < 0 || yy >= 56) continue;
            const float* r = t8 + ((size_t)(n * 32 + ci) * 56 + yy) * 56;
            float seg[13];
#pragma unroll
            for (int t = 0; t < 13; ++t) {
                int p = px0 - 3 + t;
                seg[t] = (p >= 0 && p < 56) ? r[p] : 0.f;
            }
#pragma unroll
            for (int dx = 0; dx < 7; ++dx) {
                float wv[8];
#pragma unroll
                for (int j = 0; j < 8; ++j)
                    wv[j] = Wf[((size_t)(co0 + j) * 32 + ci) * 21 + dy * 7 + dx];
#pragma unroll
                for (int j = 0; j < 8; ++j)
#pragma unroll
                    for (int p = 0; p < 7; ++p)
                        acc[j][p] += seg[p + dx] * wv[j];
            }
        }
    }
#pragma unroll
    for (int j = 0; j < 8; ++j)
#pragma unroll
        for (int p = 0; p < 7; ++p)
            row[co0 + j][px0 + p] = acc[j][p];
    __syncthreads();
    float t14v[7];
#pragma unroll
    for (int p = 0; p < 7; ++p) t14v[p] = t14[(size_t)(n * 56 + y) * 56 + px0 + p];
#pragma unroll
    for (int j = 0; j < 8; ++j) {
        int co = co0 + j;
        float wa = w16[co * 3], wb = w16[co * 3 + 1], wc = w16[co * 3 + 2];
#pragma unroll
        for (int p = 0; p < 7; ++p) {
            int xx = px0 + p;
            float s = row[co][xx] * wb;
            if (xx >= 3) s += row[co][xx - 3] * wa;
            if (xx + 3 < 56) s += row[co][xx + 3] * wc;
            out[((size_t)(n * 256 + co) * 56 + y) * 56 + xx] = s + t14v[p];
        }
    }
}

extern "C" void kernel_launch(void* const* d_in, const int* in_sizes, int n_in,
                              void* d_out, int out_size, void* d_ws, size_t ws_size,
                              hipStream_t stream) {
    const float* x   = (const float*)d_in[0];
    const float* w1  = (const float*)d_in[1];
    const float* p2w = (const float*)d_in[2];
    const float* w3  = (const float*)d_in[3];
    const float* w4  = (const float*)d_in[4];
    const float* w5  = (const float*)d_in[5];
    const float* w8  = (const float*)d_in[6];
    const float* w12 = (const float*)d_in[7];
    const float* w14 = (const float*)d_in[8];
    const float* w15 = (const float*)d_in[9];
    const float* w16 = (const float*)d_in[10];
    float* out = (float*)d_out;

    float* ws = (float*)d_ws;
    float* t1   = ws;                 // 3211264
    float* t5   = t1 + 3211264;       // 3211264
    float* t8v  = t5 + 3211264;       // 3211264
    float* t4   = t8v + 3211264;      // 100352
    float* t11  = t4 + 100352;        // 100352
    float* t14v = t11 + 100352;       // 100352
    float* W34  = t14v + 100352;      // 288
    float* Wf   = W34 + 288;          // 172032

    // weight fusions (independent of data kernels)
    fuse_w34<<<5, 64, 0, stream>>>(w3, w4, W34);
    fuse_w1215<<<672, 256, 0, stream>>>(w15, w12, Wf);

    // t1
    k_t1<<<448, 256, 0, stream>>>(x, w1, t1);
    // t4 (needs t1, W34)
    k_t4<<<1792, 64, 0, stream>>>(t1, W34, t4);
    // t5 (needs t1)
    k_t5<<<3136, 256, 0, stream>>>(t1, p2w, w5, t5);
    // t11 (needs t4)
    k_pool<<<1792, 64, 0, stream>>>(t4, t11);
    // t14 (needs t11)
    k_t14<<<1792, 64, 0, stream>>>(t11, w14, t14v);
    // t8 (needs t5)
    k_t8<<<448, 256, 0, stream>>>(t5, w8, t8v);
    // fused t15/t16/t14-add -> out (needs t8, Wf, t14)
    k_t15_out<<<1792, 256, 0, stream>>>(t8v, Wf, w16, t14v, out);
}

// Round 2
// 464.362 us; speedup vs baseline: 1.9593x; 1.9593x over previous
//
#include <hip/hip_runtime.h>
#include <hip/hip_bf16.h>
#include <cstddef>

typedef __attribute__((ext_vector_type(8))) short s8v;
typedef __attribute__((ext_vector_type(4))) float f32x4;

// ---------------- weight fusion kernels ----------------
// W34[ci][k1][k2] = sum_co w3[co,ci,k1] * w4[co,k2]   (32*3*3 = 288)
__global__ void fuse_w34(const float* __restrict__ w3, const float* __restrict__ w4,
                         float* __restrict__ W34) {
    int idx = blockIdx.x * blockDim.x + threadIdx.x;
    if (idx >= 288) return;
    int ci = idx / 9, k1 = (idx / 3) % 3, k2 = idx % 3;
    float s = 0.f;
    for (int co = 0; co < 256; ++co)
        s += w3[(co * 32 + ci) * 3 + k1] * w4[co * 3 + k2];
    W34[idx] = s;
}

// Wfb[kk][co][ci] (bf16), kk = dy*7+dx:  sum_m w15[o,3m+dy] * w12[m,ci,dx]
__global__ void fuse_w1215b(const float* __restrict__ w15, const float* __restrict__ w12,
                            __hip_bfloat16* __restrict__ Wfb) {
    int idx = blockIdx.x * blockDim.x + threadIdx.x;
    if (idx >= 21 * 256 * 32) return;
    int ci = idx & 31, co = (idx >> 5) & 255, kk = idx >> 13;
    int dy = kk / 7, dx = kk % 7;
    float s = 0.f;
    for (int m = 0; m < 256; ++m)
        s += w15[co * 768 + m * 3 + dy] * w12[(m * 32 + ci) * 7 + dx];
    Wfb[idx] = __float2bfloat16(s);
}

// ---------------- t1: conv 256->32, 3 w-taps dil 3 ----------------
__global__ __launch_bounds__(256) void k_t1(const float* __restrict__ x,
                                            const float* __restrict__ w1,
                                            float* __restrict__ t1) {
    int by = blockIdx.x;
    int n = by / 14;
    int y = (by % 14) * 4 + (threadIdx.x >> 6);
    int u = threadIdx.x & 63;
    int co0 = (u >> 3) * 4;
    int px0 = (u & 7) * 7;
    float acc[4][7] = {};
    for (int ci = 0; ci < 256; ++ci) {
        const float* xr = x + ((size_t)(n * 256 + ci) * 56 + y) * 56;
        float seg[13];
#pragma unroll
        for (int t = 0; t < 13; ++t) {
            int p = px0 - 3 + t;
            seg[t] = (p >= 0 && p < 56) ? xr[p] : 0.f;
        }
#pragma unroll
        for (int k = 0; k < 3; ++k) {
            float wv[4];
#pragma unroll
            for (int j = 0; j < 4; ++j) wv[j] = w1[(co0 + j) * 768 + ci * 3 + k];
#pragma unroll
            for (int j = 0; j < 4; ++j)
#pragma unroll
                for (int p = 0; p < 7; ++p)
                    acc[j][p] += seg[p + 3 * k] * wv[j];
        }
    }
    for (int j = 0; j < 4; ++j)
        for (int p = 0; p < 7; ++p)
            t1[((size_t)(n * 32 + co0 + j) * 56 + y) * 56 + px0 + p] = acc[j][p];
}

// ---------------- t4: 32ch, 3x3 taps dil (2,3), via W34 ----------------
__global__ void k_t4(const float* __restrict__ t1, const float* __restrict__ W34,
                     float* __restrict__ t4) {
    int by = blockIdx.x;  // N*H
    int n = by / 56, y = by % 56;
    int px = threadIdx.x;
    if (px >= 56) return;
    float acc = 0.f;
    for (int ci = 0; ci < 32; ++ci) {
#pragma unroll
        for (int k1 = 0; k1 < 3; ++k1) {
            int yy = y + 2 * k1 - 2;
            if (yy < 0 || yy >= 56) continue;
            const float* r = t1 + ((size_t)(n * 32 + ci) * 56 + yy) * 56;
#pragma unroll
            for (int k2 = 0; k2 < 3; ++k2) {
                int xx = px + 3 * k2 - 3;
                if (xx >= 0 && xx < 56)
                    acc += r[xx] * W34[ci * 9 + k1 * 3 + k2];
            }
        }
    }
    t4[(size_t)(n * 56 + y) * 56 + px] = acc;
}

// ---------------- t5: depthwise 3 h-taps dil 3, input scaled by p2w ----------------
__global__ void k_t5(const float* __restrict__ t1, const float* __restrict__ p2w,
                     const float* __restrict__ w5, float* __restrict__ t5) {
    int idx = blockIdx.x * blockDim.x + threadIdx.x;  // float4 granules
    if (idx >= 802816) return;
    int xq = idx % 14;
    int y = (idx / 14) % 56;
    int g = (idx / (14 * 56)) % 32;
    int n = idx / (14 * 56 * 32);
    float sx = 0.f, sy = 0.f, sz = 0.f, sw = 0.f;
    float scale = p2w[g];
#pragma unroll
    for (int k = 0; k < 3; ++k) {
        int yy = y + 3 * k - 3;
        if (yy < 0 || yy >= 56) continue;
        float w = w5[g * 3 + k] * scale;
        const float4 v = *(const float4*)(t1 + ((size_t)(n * 32 + g) * 56 + yy) * 56 + xq * 4);
        sx += v.x * w; sy += v.y * w; sz += v.z * w; sw += v.w * w;
    }
    float4 s = {sx, sy, sz, sw};
    *(float4*)(t5 + (size_t)idx * 4) = s;
}

// ---------------- pool: t4 -> t11 ----------------
__global__ void k_pool(const float* __restrict__ t4, float* __restrict__ t11) {
    int by = blockIdx.x;
    int n = by / 56, y = by % 56;
    int px = threadIdx.x;
    if (px >= 56) return;
    float s = 0.f;
    for (int j = 0; j < 7; ++j) {
        int xx = px + 3 * j - 9;
        bool xin = (xx >= 0 && xx < 56);
        for (int dy = -1; dy <= 1; ++dy) {
            int yc = y + dy;
            if (yc < 0 || yc >= 56) continue;
            float m = -3.4e38f;
            for (int i = 0; i < 7; ++i) {
                int yy = yc + 3 * i - 9;
                float v = (xin && yy >= 0 && yy < 56) ? t4[(size_t)(n * 56 + yy) * 56 + xx] : 0.f;
                m = fmaxf(m, v);
            }
            s += fmaxf(m, 0.f);
        }
    }
    t11[(size_t)(n * 56 + y) * 56 + px] = s * (1.f / 21.f);
}

// ---------------- t14: 3x3 conv on t11 ----------------
__global__ void k_t14(const float* __restrict__ t11, const float* __restrict__ w14,
                      float* __restrict__ t14) {
    int by = blockIdx.x;
    int n = by / 56, y = by % 56;
    int px = threadIdx.x;
    if (px >= 56) return;
    float s = 0.f;
#pragma unroll
    for (int dy = 0; dy < 3; ++dy) {
        int yy = y + dy - 1;
        if (yy < 0 || yy >= 56) continue;
#pragma unroll
        for (int dx = 0; dx < 3; ++dx) {
            int xx = px + dx - 1;
            if (xx < 0 || xx >= 56) continue;
            s += t11[(size_t)(n * 56 + yy) * 56 + xx] * w14[dy * 3 + dx];
        }
    }
    t14[(size_t)(n * 56 + y) * 56 + px] = s;
}

// ---------------- t8: conv 32->32, 7 w-taps dil 2, bf16 out ----------------
__global__ __launch_bounds__(256) void k_t8(const float* __restrict__ t5,
                                            const float* __restrict__ w8,
                                            __hip_bfloat16* __restrict__ t8b) {
    int by = blockIdx.x;  // 448
    int n = by / 14;
    int y = (by % 14) * 4 + (threadIdx.x >> 6);
    int u = threadIdx.x & 63;
    int co0 = (u >> 3) * 4;
    int px0 = (u & 7) * 7;
    float acc[4][7] = {};
    for (int ci = 0; ci < 32; ++ci) {
        const float* r = t5 + ((size_t)(n * 32 + ci) * 56 + y) * 56;
        float seg[19];
#pragma unroll
        for (int t = 0; t < 19; ++t) {
            int p = px0 - 6 + t;
            seg[t] = (p >= 0 && p < 56) ? r[p] : 0.f;
        }
#pragma unroll
        for (int j = 0; j < 7; ++j) {
            float wv[4];
#pragma unroll
            for (int q = 0; q < 4; ++q) wv[q] = w8[(co0 + q) * 224 + ci * 7 + j];
#pragma unroll
            for (int q = 0; q < 4; ++q)
#pragma unroll
                for (int p = 0; p < 7; ++p)
                    acc[q][p] += seg[p + 2 * j] * wv[q];
        }
    }
    for (int q = 0; q < 4; ++q)
        for (int p = 0; p < 7; ++p)
            t8b[((size_t)(n * 32 + co0 + q) * 56 + y) * 56 + px0 + p] = __float2bfloat16(acc[q][p]);
}

// ---------------- MFMA fused kernel: t8b -> t15 -> t16 + t14 -> out ----------------
// grid N*H = 1792, block 256 (4 waves). Per block: out tile 256co x 56px (one row).
// K = 21 steps of (dy,dx) x 32ci.  mfma_f32_16x16x32_bf16, wave w: co [w*64, w*64+64).
__global__ __launch_bounds__(256) void k_t15m(const unsigned short* __restrict__ t8b,
                                              const unsigned short* __restrict__ Wfb,
                                              const float* __restrict__ w16,
                                              const float* __restrict__ t14,
                                              float* __restrict__ out) {
    __shared__ __align__(16) char lds[33792];
    const int t = threadIdx.x;
    const int by = blockIdx.x;
    const int n = by / 56, y = by % 56;
    const int l = t & 63, h = l >> 4, q = l & 15;
    const int co0 = (t >> 6) * 64;

    // ---- stage S: [dy 3][x' 72][ci 32] bf16 (x' = x+3), XOR-swizzled ----
    for (int idx = t; idx < 6912; idx += 256) {
        int xp = idx % 72;
        int rem = idx / 72;          // dy*32 + ci
        int ci = rem & 31;
        int dy = rem >> 5;
        int xx = xp - 3, yy = y + 2 * dy - 2;
        unsigned short val = 0;
        if (xx >= 0 && xx < 56 && yy >= 0 && yy < 56)
            val = t8b[((size_t)(n * 32 + ci) * 56 + yy) * 56 + xx];
        int dst = 16384 + dy * 4608 + xp * 64 + ((((ci >> 3) ^ ((xp >> 1) & 3))) << 4) + (ci & 7) * 2;
        *(unsigned short*)(lds + dst) = val;
    }

    f32x4 acc[4][4];
#pragma unroll
    for (int m = 0; m < 4; ++m)
#pragma unroll
        for (int nt = 0; nt < 4; ++nt)
            acc[m][nt] = (f32x4)0.f;

    for (int kk = 0; kk < 21; ++kk) {
        int dy = kk / 7, dx = kk - dy * 7;
        int yy = y + 2 * dy - 2;
        if (yy < 0 || yy >= 56) continue;   // block-uniform
        __syncthreads();
        // stage A chunk [co 256][ci 32] bf16, swizzled; 1024 x 16B
#pragma unroll
        for (int i = 0; i < 4; ++i) {
            int c = t + i * 256;
            int co = c >> 2, hh = c & 3;
            s8v v = *reinterpret_cast<const s8v*>(Wfb + (size_t)kk * 8192 + c * 8);
            *reinterpret_cast<s8v*>(lds + co * 64 + ((hh ^ ((co >> 1) & 3)) << 4)) = v;
        }
        __syncthreads();
        s8v af[4];
#pragma unroll
        for (int m = 0; m < 4; ++m) {
            int co = co0 + m * 16 + q;
            af[m] = *reinterpret_cast<const s8v*>(lds + co * 64 + ((h ^ ((co >> 1) & 3)) << 4));
        }
#pragma unroll
        for (int nt = 0; nt < 4; ++nt) {
            int xp = nt * 16 + q + dx;
            s8v bf = *reinterpret_cast<const s8v*>(
                lds + 16384 + dy * 4608 + xp * 64 + ((h ^ ((xp >> 1) & 3)) << 4));
#pragma unroll
            for (int m = 0; m < 4; ++m)
                acc[m][nt] = __builtin_amdgcn_mfma_f32_16x16x32_bf16(af[m], bf, acc[m][nt], 0, 0, 0);
        }
    }

    __syncthreads();
    // ---- rowbuf [co 256][x 66] bf16 (reuses LDS) ----
#pragma unroll
    for (int m = 0; m < 4; ++m)
#pragma unroll
        for (int nt = 0; nt < 4; ++nt)
#pragma unroll
            for (int r = 0; r < 4; ++r) {
                int co = co0 + m * 16 + h * 4 + r;
                int x = nt * 16 + q;
                *reinterpret_cast<__hip_bfloat16*>(lds + (co * 66 + x) * 2) =
                    __float2bfloat16(acc[m][nt][r]);
            }
    __syncthreads();

    // ---- t16 (depthwise, 3 taps dil 3) + t14 -> out ----
    int xg = t & 7;
    float t14v[7];
    const float* t14r = t14 + (size_t)(n * 56 + y) * 56;
#pragma unroll
    for (int p = 0; p < 7; ++p) t14v[p] = t14r[xg * 7 + p];
    for (int cb = 0; cb < 256; cb += 32) {
        int co = cb + (t >> 3);
        float wa = w16[co * 3], wb = w16[co * 3 + 1], wc = w16[co * 3 + 2];
        float* orow = out + ((size_t)(n * 256 + co) * 56 + y) * 56;
#pragma unroll
        for (int p = 0; p < 7; ++p) {
            int x = xg * 7 + p;
            float s = __bfloat162float(*reinterpret_cast<const __hip_bfloat16*>(lds + (co * 66 + x) * 2)) * wb + t14v[p];
            if (x >= 3)
                s += __bfloat162float(*reinterpret_cast<const __hip_bfloat16*>(lds + (co * 66 + x - 3) * 2)) * wa;
            if (x <= 52)
                s += __bfloat162float(*reinterpret_cast<const __hip_bfloat16*>(lds + (co * 66 + x + 3) * 2)) * wc;
            orow[x] = s;
        }
    }
}

extern "C" void kernel_launch(void* const* d_in, const int* in_sizes, int n_in,
                              void* d_out, int out_size, void* d_ws, size_t ws_size,
                              hipStream_t stream) {
    const float* x   = (const float*)d_in[0];
    const float* w1  = (const float*)d_in[1];
    const float* p2w = (const float*)d_in[2];
    const float* w3  = (const float*)d_in[3];
    const float* w4  = (const float*)d_in[4];
    const float* w5  = (const float*)d_in[5];
    const float* w8  = (const float*)d_in[6];
    const float* w12 = (const float*)d_in[7];
    const float* w14 = (const float*)d_in[8];
    const float* w15 = (const float*)d_in[9];
    const float* w16 = (const float*)d_in[10];
    float* out = (float*)d_out;

    float* ws = (float*)d_ws;
    float* t1   = ws;                  // 3211264 f32
    float* t5   = t1 + 3211264;        // 3211264 f32
    float* t4   = t5 + 3211264;        // 100352 f32
    float* t11  = t4 + 100352;         // 100352 f32
    float* t14v = t11 + 100352;        // 100352 f32
    float* W34  = t14v + 100352;       // 288 f32
    __hip_bfloat16* t8b = (__hip_bfloat16*)(W34 + 288);   // 3211264 bf16 (16B-aligned)
    __hip_bfloat16* Wfb = t8b + 3211264;                  // 172032 bf16

    fuse_w34<<<5, 64, 0, stream>>>(w3, w4, W34);
    fuse_w1215b<<<672, 256, 0, stream>>>(w15, w12, Wfb);

    k_t1<<<448, 256, 0, stream>>>(x, w1, t1);
    k_t4<<<1792, 64, 0, stream>>>(t1, W34, t4);
    k_t5<<<3136, 256, 0, stream>>>(t1, p2w, w5, t5);
    k_pool<<<1792, 64, 0, stream>>>(t4, t11);
    k_t14<<<1792, 64, 0, stream>>>(t11, w14, t14v);
    k_t8<<<448, 256, 0, stream>>>(t5, w8, t8b);
    k_t15m<<<1792, 256, 0, stream>>>((const unsigned short*)t8b, (const unsigned short*)Wfb,
                                     w16, t14v, out);
}

// Round 3
// 400.192 us; speedup vs baseline: 2.2735x; 1.1603x over previous
//
#include <hip/hip_runtime.h>
#include <hip/hip_bf16.h>
#include <cstddef>

typedef __attribute__((ext_vector_type(8))) short s8v;
typedef __attribute__((ext_vector_type(4))) float f32x4;

// ---------------- weight fusion kernels ----------------
// W34[ci][k1][k2] = sum_co w3[co,ci,k1] * w4[co,k2]   (32*3*3 = 288)
__global__ void fuse_w34(const float* __restrict__ w3, const float* __restrict__ w4,
                         float* __restrict__ W34) {
    int idx = blockIdx.x * blockDim.x + threadIdx.x;
    if (idx >= 288) return;
    int ci = idx / 9, k1 = (idx / 3) % 3, k2 = idx % 3;
    float s = 0.f;
    for (int co = 0; co < 256; ++co)
        s += w3[(co * 32 + ci) * 3 + k1] * w4[co * 3 + k2];
    W34[idx] = s;
}

// Wfb[kk][co][ci] (bf16), kk = dy*7+dx:  sum_m w15[o,3m+dy] * w12[m,ci,dx]
__global__ void fuse_w1215b(const float* __restrict__ w15, const float* __restrict__ w12,
                            __hip_bfloat16* __restrict__ Wfb) {
    int idx = blockIdx.x * blockDim.x + threadIdx.x;
    if (idx >= 21 * 256 * 32) return;
    int ci = idx & 31, co = (idx >> 5) & 255, kk = idx >> 13;
    int dy = kk / 7, dx = kk % 7;
    float s = 0.f;
    for (int m = 0; m < 256; ++m)
        s += w15[co * 768 + m * 3 + dy] * w12[(m * 32 + ci) * 7 + dx];
    Wfb[idx] = __float2bfloat16(s);
}

// w1b[k][c][h][co][j]: bf16 repack of w1 (co,ci,k), ci = c*32+h*8+j.
// A-fragment for wave: 16 lanes x 16B contiguous per h -> coalesced L2 loads.
__global__ void fuse_w1b(const float* __restrict__ w1, __hip_bfloat16* __restrict__ w1b) {
    int idx = blockIdx.x * blockDim.x + threadIdx.x;
    if (idx >= 24576) return;
    int j = idx & 7, co = (idx >> 3) & 31, h = (idx >> 8) & 3, c = (idx >> 10) & 7, k = idx >> 13;
    int ci = c * 32 + h * 8 + j;
    w1b[idx] = __float2bfloat16(w1[(co * 256 + ci) * 3 + k]);
}

// ---------------- t1 MFMA: conv 256->32, 3 w-taps dil 3 ----------------
// grid 448 (N*H/4), block 256 = 4 waves; wave w owns row y0+w, co 0..31, px 0..63.
// K = 8 chunks of 32 ci; per chunk 3 taps (shifted B reads). B double-buffered in LDS.
__global__ __launch_bounds__(256) void k_t1m(const float* __restrict__ x,
                                             const unsigned short* __restrict__ w1b,
                                             float* __restrict__ t1) {
    __shared__ __align__(16) char lds[36864];  // 2 x [4 rows][72 xp][32 ci] bf16, swizzled
    const int t = threadIdx.x;
    const int b = blockIdx.x;
    const int n = b / 14, y0 = (b % 14) * 4;
    const int w = t >> 6, l = t & 63, h = l >> 4, q = l & 15;
    const int y = y0 + w;

    const float* xb = x + (size_t)n * 256 * 3136;

    f32x4 acc[2][4];
#pragma unroll
    for (int m = 0; m < 2; ++m)
#pragma unroll
        for (int nt = 0; nt < 4; ++nt) acc[m][nt] = (f32x4)0.f;

#define STAGE(c, buf)                                                                  \
    {                                                                                  \
        char* base = lds + (buf)*18432;                                                \
        for (int i = 0; i < 36; ++i) {                                                 \
            int e = i * 256 + t;                                                       \
            int xp = e % 72;                                                           \
            int rr = (e / 72) & 3;                                                     \
            int ci = e / 288;                                                          \
            int xx = xp - 3;                                                           \
            float v = 0.f;                                                             \
            if (xx >= 0 && xx < 56)                                                    \
                v = xb[(size_t)((c)*32 + ci) * 3136 + (y0 + rr) * 56 + xx];            \
            int dst = (rr * 72 + xp) * 64 + ((((ci >> 3) ^ ((xp >> 1) & 3))) << 4) +   \
                      (ci & 7) * 2;                                                    \
            *(__hip_bfloat16*)(base + dst) = __float2bfloat16(v);                      \
        }                                                                              \
    }

    STAGE(0, 0);
    for (int c = 0; c < 8; ++c) {
        __syncthreads();
        if (c < 7) STAGE(c + 1, (c + 1) & 1);
        const char* base = lds + (c & 1) * 18432;
#pragma unroll
        for (int k = 0; k < 3; ++k) {
            s8v af[2];
#pragma unroll
            for (int m = 0; m < 2; ++m)
                af[m] = *reinterpret_cast<const s8v*>(
                    w1b + (size_t)((((k * 8 + c) * 4 + h) * 32 + m * 16 + q) * 8));
#pragma unroll
            for (int nt = 0; nt < 4; ++nt) {
                int xp = nt * 16 + q + 3 * k;
                s8v bf = *reinterpret_cast<const s8v*>(
                    base + (w * 72 + xp) * 64 + ((h ^ ((xp >> 1) & 3)) << 4));
                acc[0][nt] = __builtin_amdgcn_mfma_f32_16x16x32_bf16(af[0], bf, acc[0][nt], 0, 0, 0);
                acc[1][nt] = __builtin_amdgcn_mfma_f32_16x16x32_bf16(af[1], bf, acc[1][nt], 0, 0, 0);
            }
        }
    }
#undef STAGE

#pragma unroll
    for (int m = 0; m < 2; ++m)
#pragma unroll
        for (int nt = 0; nt < 4; ++nt) {
            int px = nt * 16 + q;
            if (px < 56) {
#pragma unroll
                for (int r = 0; r < 4; ++r) {
                    int co = m * 16 + h * 4 + r;
                    t1[((size_t)(n * 32 + co) * 56 + y) * 56 + px] = acc[m][nt][r];
                }
            }
        }
}

// ---------------- t4: 32ch, 3x3 taps dil (2,3), via W34 ----------------
__global__ void k_t4(const float* __restrict__ t1, const float* __restrict__ W34,
                     float* __restrict__ t4) {
    int by = blockIdx.x;  // N*H
    int n = by / 56, y = by % 56;
    int px = threadIdx.x;
    if (px >= 56) return;
    float acc = 0.f;
    for (int ci = 0; ci < 32; ++ci) {
#pragma unroll
        for (int k1 = 0; k1 < 3; ++k1) {
            int yy = y + 2 * k1 - 2;
            if (yy < 0 || yy >= 56) continue;
            const float* r = t1 + ((size_t)(n * 32 + ci) * 56 + yy) * 56;
#pragma unroll
            for (int k2 = 0; k2 < 3; ++k2) {
                int xx = px + 3 * k2 - 3;
                if (xx >= 0 && xx < 56)
                    acc += r[xx] * W34[ci * 9 + k1 * 3 + k2];
            }
        }
    }
    t4[(size_t)(n * 56 + y) * 56 + px] = acc;
}

// ---------------- t5: depthwise 3 h-taps dil 3, input scaled by p2w ----------------
__global__ void k_t5(const float* __restrict__ t1, const float* __restrict__ p2w,
                     const float* __restrict__ w5, float* __restrict__ t5) {
    int idx = blockIdx.x * blockDim.x + threadIdx.x;  // float4 granules
    if (idx >= 802816) return;
    int xq = idx % 14;
    int y = (idx / 14) % 56;
    int g = (idx / (14 * 56)) % 32;
    int n = idx / (14 * 56 * 32);
    float sx = 0.f, sy = 0.f, sz = 0.f, sw = 0.f;
    float scale = p2w[g];
#pragma unroll
    for (int k = 0; k < 3; ++k) {
        int yy = y + 3 * k - 3;
        if (yy < 0 || yy >= 56) continue;
        float w = w5[g * 3 + k] * scale;
        const float4 v = *(const float4*)(t1 + ((size_t)(n * 32 + g) * 56 + yy) * 56 + xq * 4);
        sx += v.x * w; sy += v.y * w; sz += v.z * w; sw += v.w * w;
    }
    float4 s = {sx, sy, sz, sw};
    *(float4*)(t5 + (size_t)idx * 4) = s;
}

// ---------------- pool: t4 -> t11 ----------------
__global__ void k_pool(const float* __restrict__ t4, float* __restrict__ t11) {
    int by = blockIdx.x;
    int n = by / 56, y = by % 56;
    int px = threadIdx.x;
    if (px >= 56) return;
    float s = 0.f;
    for (int j = 0; j < 7; ++j) {
        int xx = px + 3 * j - 9;
        bool xin = (xx >= 0 && xx < 56);
        for (int dy = -1; dy <= 1; ++dy) {
            int yc = y + dy;
            if (yc < 0 || yc >= 56) continue;
            float m = -3.4e38f;
            for (int i = 0; i < 7; ++i) {
                int yy = yc + 3 * i - 9;
                float v = (xin && yy >= 0 && yy < 56) ? t4[(size_t)(n * 56 + yy) * 56 + xx] : 0.f;
                m = fmaxf(m, v);
            }
            s += fmaxf(m, 0.f);
        }
    }
    t11[(size_t)(n * 56 + y) * 56 + px] = s * (1.f / 21.f);
}

// ---------------- t14: 3x3 conv on t11 ----------------
__global__ void k_t14(const float* __restrict__ t11, const float* __restrict__ w14,
                      float* __restrict__ t14) {
    int by = blockIdx.x;
    int n = by / 56, y = by % 56;
    int px = threadIdx.x;
    if (px >= 56) return;
    float s = 0.f;
#pragma unroll
    for (int dy = 0; dy < 3; ++dy) {
        int yy = y + dy - 1;
        if (yy < 0 || yy >= 56) continue;
#pragma unroll
        for (int dx = 0; dx < 3; ++dx) {
            int xx = px + dx - 1;
            if (xx < 0 || xx >= 56) continue;
            s += t11[(size_t)(n * 56 + yy) * 56 + xx] * w14[dy * 3 + dx];
        }
    }
    t14[(size_t)(n * 56 + y) * 56 + px] = s;
}

// ---------------- t8: conv 32->32, 7 w-taps dil 2, bf16 out ----------------
__global__ __launch_bounds__(256) void k_t8(const float* __restrict__ t5,
                                            const float* __restrict__ w8,
                                            __hip_bfloat16* __restrict__ t8b) {
    int by = blockIdx.x;  // 448
    int n = by / 14;
    int y = (by % 14) * 4 + (threadIdx.x >> 6);
    int u = threadIdx.x & 63;
    int co0 = (u >> 3) * 4;
    int px0 = (u & 7) * 7;
    float acc[4][7] = {};
    for (int ci = 0; ci < 32; ++ci) {
        const float* r = t5 + ((size_t)(n * 32 + ci) * 56 + y) * 56;
        float seg[19];
#pragma unroll
        for (int t = 0; t < 19; ++t) {
            int p = px0 - 6 + t;
            seg[t] = (p >= 0 && p < 56) ? r[p] : 0.f;
        }
#pragma unroll
        for (int j = 0; j < 7; ++j) {
            float wv[4];
#pragma unroll
            for (int q = 0; q < 4; ++q) wv[q] = w8[(co0 + q) * 224 + ci * 7 + j];
#pragma unroll
            for (int q = 0; q < 4; ++q)
#pragma unroll
                for (int p = 0; p < 7; ++p)
                    acc[q][p] += seg[p + 2 * j] * wv[q];
        }
    }
    for (int q = 0; q < 4; ++q)
        for (int p = 0; p < 7; ++p)
            t8b[((size_t)(n * 32 + co0 + q) * 56 + y) * 56 + px0 + p] = __float2bfloat16(acc[q][p]);
}

// ---------------- MFMA fused kernel: t8b -> t15 -> t16 + t14 -> out ----------------
__global__ __launch_bounds__(256) void k_t15m(const unsigned short* __restrict__ t8b,
                                              const unsigned short* __restrict__ Wfb,
                                              const float* __restrict__ w16,
                                              const float* __restrict__ t14,
                                              float* __restrict__ out) {
    __shared__ __align__(16) char lds[33792];
    const int t = threadIdx.x;
    const int by = blockIdx.x;
    const int n = by / 56, y = by % 56;
    const int l = t & 63, h = l >> 4, q = l & 15;
    const int co0 = (t >> 6) * 64;

    // ---- stage S: [dy 3][x' 72][ci 32] bf16 (x' = x+3), XOR-swizzled ----
    for (int idx = t; idx < 6912; idx += 256) {
        int xp = idx % 72;
        int rem = idx / 72;          // dy*32 + ci
        int ci = rem & 31;
        int dy = rem >> 5;
        int xx = xp - 3, yy = y + 2 * dy - 2;
        unsigned short val = 0;
        if (xx >= 0 && xx < 56 && yy >= 0 && yy < 56)
            val = t8b[((size_t)(n * 32 + ci) * 56 + yy) * 56 + xx];
        int dst = 16384 + dy * 4608 + xp * 64 + ((((ci >> 3) ^ ((xp >> 1) & 3))) << 4) + (ci & 7) * 2;
        *(unsigned short*)(lds + dst) = val;
    }

    f32x4 acc[4][4];
#pragma unroll
    for (int m = 0; m < 4; ++m)
#pragma unroll
        for (int nt = 0; nt < 4; ++nt)
            acc[m][nt] = (f32x4)0.f;

    for (int kk = 0; kk < 21; ++kk) {
        int dy = kk / 7, dx = kk - dy * 7;
        int yy = y + 2 * dy - 2;
        if (yy < 0 || yy >= 56) continue;   // block-uniform
        __syncthreads();
        // stage A chunk [co 256][ci 32] bf16, swizzled; 1024 x 16B
#pragma unroll
        for (int i = 0; i < 4; ++i) {
            int c = t + i * 256;
            int co = c >> 2, hh = c & 3;
            s8v v = *reinterpret_cast<const s8v*>(Wfb + (size_t)kk * 8192 + c * 8);
            *reinterpret_cast<s8v*>(lds + co * 64 + ((hh ^ ((co >> 1) & 3)) << 4)) = v;
        }
        __syncthreads();
        s8v af[4];
#pragma unroll
        for (int m = 0; m < 4; ++m) {
            int co = co0 + m * 16 + q;
            af[m] = *reinterpret_cast<const s8v*>(lds + co * 64 + ((h ^ ((co >> 1) & 3)) << 4));
        }
#pragma unroll
        for (int nt = 0; nt < 4; ++nt) {
            int xp = nt * 16 + q + dx;
            s8v bf = *reinterpret_cast<const s8v*>(
                lds + 16384 + dy * 4608 + xp * 64 + ((h ^ ((xp >> 1) & 3)) << 4));
#pragma unroll
            for (int m = 0; m < 4; ++m)
                acc[m][nt] = __builtin_amdgcn_mfma_f32_16x16x32_bf16(af[m], bf, acc[m][nt], 0, 0, 0);
        }
    }

    __syncthreads();
    // ---- rowbuf [co 256][x 66] bf16 (reuses LDS) ----
#pragma unroll
    for (int m = 0; m < 4; ++m)
#pragma unroll
        for (int nt = 0; nt < 4; ++nt)
#pragma unroll
            for (int r = 0; r < 4; ++r) {
                int co = co0 + m * 16 + h * 4 + r;
                int x = nt * 16 + q;
                *reinterpret_cast<__hip_bfloat16*>(lds + (co * 66 + x) * 2) =
                    __float2bfloat16(acc[m][nt][r]);
            }
    __syncthreads();

    // ---- t16 (depthwise, 3 taps dil 3) + t14 -> out ----
    int xg = t & 7;
    float t14v[7];
    const float* t14r = t14 + (size_t)(n * 56 + y) * 56;
#pragma unroll
    for (int p = 0; p < 7; ++p) t14v[p] = t14r[xg * 7 + p];
    for (int cb = 0; cb < 256; cb += 32) {
        int co = cb + (t >> 3);
        float wa = w16[co * 3], wb = w16[co * 3 + 1], wc = w16[co * 3 + 2];
        float* orow = out + ((size_t)(n * 256 + co) * 56 + y) * 56;
#pragma unroll
        for (int p = 0; p < 7; ++p) {
            int x = xg * 7 + p;
            float s = __bfloat162float(*reinterpret_cast<const __hip_bfloat16*>(lds + (co * 66 + x) * 2)) * wb + t14v[p];
            if (x >= 3)
                s += __bfloat162float(*reinterpret_cast<const __hip_bfloat16*>(lds + (co * 66 + x - 3) * 2)) * wa;
            if (x <= 52)
                s += __bfloat162float(*reinterpret_cast<const __hip_bfloat16*>(lds + (co * 66 + x + 3) * 2)) * wc;
            orow[x] = s;
        }
    }
}

extern "C" void kernel_launch(void* const* d_in, const int* in_sizes, int n_in,
                              void* d_out, int out_size, void* d_ws, size_t ws_size,
                              hipStream_t stream) {
    const float* x   = (const float*)d_in[0];
    const float* w1  = (const float*)d_in[1];
    const float* p2w = (const float*)d_in[2];
    const float* w3  = (const float*)d_in[3];
    const float* w4  = (const float*)d_in[4];
    const float* w5  = (const float*)d_in[5];
    const float* w8  = (const float*)d_in[6];
    const float* w12 = (const float*)d_in[7];
    const float* w14 = (const float*)d_in[8];
    const float* w15 = (const float*)d_in[9];
    const float* w16 = (const float*)d_in[10];
    float* out = (float*)d_out;

    float* ws = (float*)d_ws;
    float* t1   = ws;                  // 3211264 f32
    float* t5   = t1 + 3211264;        // 3211264 f32
    float* t4   = t5 + 3211264;        // 100352 f32
    float* t11  = t4 + 100352;         // 100352 f32
    float* t14v = t11 + 100352;        // 100352 f32
    float* W34  = t14v + 100352;       // 288 f32
    __hip_bfloat16* t8b = (__hip_bfloat16*)(W34 + 288);   // 3211264 bf16 (16B-aligned)
    __hip_bfloat16* Wfb = t8b + 3211264;                  // 172032 bf16
    __hip_bfloat16* w1b = Wfb + 172032;                   // 24576 bf16

    fuse_w34<<<5, 64, 0, stream>>>(w3, w4, W34);
    fuse_w1215b<<<672, 256, 0, stream>>>(w15, w12, Wfb);
    fuse_w1b<<<96, 256, 0, stream>>>(w1, w1b);

    k_t1m<<<448, 256, 0, stream>>>(x, (const unsigned short*)w1b, t1);
    k_t4<<<1792, 64, 0, stream>>>(t1, W34, t4);
    k_t5<<<3136, 256, 0, stream>>>(t1, p2w, w5, t5);
    k_pool<<<1792, 64, 0, stream>>>(t4, t11);
    k_t14<<<1792, 64, 0, stream>>>(t11, w14, t14v);
    k_t8<<<448, 256, 0, stream>>>(t5, w8, t8b);
    k_t15m<<<1792, 256, 0, stream>>>((const unsigned short*)t8b, (const unsigned short*)Wfb,
                                     w16, t14v, out);
}

// Round 4
// 349.198 us; speedup vs baseline: 2.6055x; 1.1460x over previous
//
#include <hip/hip_runtime.h>
#include <hip/hip_bf16.h>
#include <cstddef>

typedef __attribute__((ext_vector_type(8))) short s8v;
typedef __attribute__((ext_vector_type(4))) float f32x4;

// ---------------- weight fusion kernels ----------------
// W34[ci][k1][k2] = sum_co w3[co,ci,k1] * w4[co,k2]   (32*3*3 = 288)
__global__ void fuse_w34(const float* __restrict__ w3, const float* __restrict__ w4,
                         float* __restrict__ W34) {
    int idx = blockIdx.x * blockDim.x + threadIdx.x;
    if (idx >= 288) return;
    int ci = idx / 9, k1 = (idx / 3) % 3, k2 = idx % 3;
    float s = 0.f;
    for (int co = 0; co < 256; ++co)
        s += w3[(co * 32 + ci) * 3 + k1] * w4[co * 3 + k2];
    W34[idx] = s;
}

// Wfb[kk][co][ci] (bf16), kk = dy*7+dx:  sum_m w15[o,3m+dy] * w12[m,ci,dx]
__global__ void fuse_w1215b(const float* __restrict__ w15, const float* __restrict__ w12,
                            __hip_bfloat16* __restrict__ Wfb) {
    int idx = blockIdx.x * blockDim.x + threadIdx.x;
    if (idx >= 21 * 256 * 32) return;
    int ci = idx & 31, co = (idx >> 5) & 255, kk = idx >> 13;
    int dy = kk / 7, dx = kk % 7;
    float s = 0.f;
    for (int m = 0; m < 256; ++m)
        s += w15[co * 768 + m * 3 + dy] * w12[(m * 32 + ci) * 7 + dx];
    Wfb[idx] = __float2bfloat16(s);
}

// w1b[k][c][h][co][j]: bf16 repack of w1 (co,ci,k), ci = c*32+h*8+j.
__global__ void fuse_w1b(const float* __restrict__ w1, __hip_bfloat16* __restrict__ w1b) {
    int idx = blockIdx.x * blockDim.x + threadIdx.x;
    if (idx >= 24576) return;
    int j = idx & 7, co = (idx >> 3) & 31, h = (idx >> 8) & 3, c = (idx >> 10) & 7, k = idx >> 13;
    int ci = c * 32 + h * 8 + j;
    w1b[idx] = __float2bfloat16(w1[(co * 256 + ci) * 3 + k]);
}

// ---------------- t1 fused MFMA: conv 256->32, 3 w-taps dil 3 ----------------
// grid 1792 (n,y), block 256 = 4 waves. Per block: out 32co x 56px (one row).
// In-LDS transpose stage [70 pos][32 g(8ci)] bf16, slot-swizzled; K=768 split
// across waves (wave w: ci [64w,64w+64) x 3 taps); LDS reduction; wave0 stores.
__global__ __launch_bounds__(256) void k_t1f(const float* __restrict__ x,
                                             const unsigned short* __restrict__ w1b,
                                             float* __restrict__ t1) {
    __shared__ __align__(16) char lds[36864];
    const int t = threadIdx.x, b = blockIdx.x;
    const int n = b / 56, y = b % 56;
    const int w = t >> 6, l = t & 63, h = l >> 4, q = l & 15;
    const float* xr = x + (size_t)(n * 256) * 3136 + y * 56;  // + ci*3136 + xx

    // ---- stage: 2240 16B-units = [70 pos][32 g] bf16, slot = g ^ (pos&15) ----
    for (int it = 0; it < 9; ++it) {
        int u = it * 256 + t;
        if (u < 2240) {
            int pos = u >> 5, g = u & 31;
            int xx = pos - 3;
            s8v sv;
#pragma unroll
            for (int j = 0; j < 8; ++j) {
                float v = 0.f;
                if (xx >= 0 && xx < 56) v = xr[(size_t)(8 * g + j) * 3136 + xx];
                __hip_bfloat16 bv = __float2bfloat16(v);
                ((unsigned short*)&sv)[j] = *(unsigned short*)&bv;
            }
            *reinterpret_cast<s8v*>(lds + pos * 512 + ((g ^ (pos & 15)) << 4)) = sv;
        }
    }
    __syncthreads();

    f32x4 acc[2][4];
#pragma unroll
    for (int m = 0; m < 2; ++m)
#pragma unroll
        for (int nt = 0; nt < 4; ++nt) acc[m][nt] = (f32x4)0.f;

    // ---- K-loop: wave w handles ci-chunks {2w, 2w+1}; no barriers ----
    for (int cc = 0; cc < 2; ++cc) {
        const int c = 2 * w + cc;
        const int g = c * 4 + h;
#pragma unroll
        for (int k = 0; k < 3; ++k) {
            s8v af[2];
#pragma unroll
            for (int m = 0; m < 2; ++m)
                af[m] = *reinterpret_cast<const s8v*>(
                    w1b + (size_t)((((k * 8 + c) * 4 + h) * 32 + m * 16 + q) * 8));
#pragma unroll
            for (int nt = 0; nt < 4; ++nt) {
                int pos = nt * 16 + q + 3 * k;
                s8v bf = *reinterpret_cast<const s8v*>(lds + pos * 512 + ((g ^ (pos & 15)) << 4));
                acc[0][nt] = __builtin_amdgcn_mfma_f32_16x16x32_bf16(af[0], bf, acc[0][nt], 0, 0, 0);
                acc[1][nt] = __builtin_amdgcn_mfma_f32_16x16x32_bf16(af[1], bf, acc[1][nt], 0, 0, 0);
            }
        }
    }

    // ---- reduce 4 partial K-sums via LDS, wave 0 stores ----
    __syncthreads();
    if (w > 0) {
#pragma unroll
        for (int m = 0; m < 2; ++m)
#pragma unroll
            for (int nt = 0; nt < 4; ++nt)
                *reinterpret_cast<f32x4*>(lds + (((w - 1) * 8 + m * 4 + nt) * 64 + l) * 16) =
                    acc[m][nt];
    }
    __syncthreads();
    if (w == 0) {
#pragma unroll
        for (int m = 0; m < 2; ++m)
#pragma unroll
            for (int nt = 0; nt < 4; ++nt) {
                f32x4 a = acc[m][nt];
#pragma unroll
                for (int s = 0; s < 3; ++s)
                    a += *reinterpret_cast<const f32x4*>(
                        lds + ((s * 8 + m * 4 + nt) * 64 + l) * 16);
                int px = nt * 16 + q;
                if (px < 56) {
#pragma unroll
                    for (int r = 0; r < 4; ++r)
                        t1[((size_t)(n * 32 + m * 16 + h * 4 + r) * 56 + y) * 56 + px] = a[r];
                }
            }
    }
}

// ---------------- t4: 32ch, 3x3 taps dil (2,3), via W34 ----------------
__global__ void k_t4(const float* __restrict__ t1, const float* __restrict__ W34,
                     float* __restrict__ t4) {
    int by = blockIdx.x;  // N*H
    int n = by / 56, y = by % 56;
    int px = threadIdx.x;
    if (px >= 56) return;
    float acc = 0.f;
    for (int ci = 0; ci < 32; ++ci) {
#pragma unroll
        for (int k1 = 0; k1 < 3; ++k1) {
            int yy = y + 2 * k1 - 2;
            if (yy < 0 || yy >= 56) continue;
            const float* r = t1 + ((size_t)(n * 32 + ci) * 56 + yy) * 56;
#pragma unroll
            for (int k2 = 0; k2 < 3; ++k2) {
                int xx = px + 3 * k2 - 3;
                if (xx >= 0 && xx < 56)
                    acc += r[xx] * W34[ci * 9 + k1 * 3 + k2];
            }
        }
    }
    t4[(size_t)(n * 56 + y) * 56 + px] = acc;
}

// ---------------- t5: depthwise 3 h-taps dil 3, input scaled by p2w ----------------
__global__ void k_t5(const float* __restrict__ t1, const float* __restrict__ p2w,
                     const float* __restrict__ w5, float* __restrict__ t5) {
    int idx = blockIdx.x * blockDim.x + threadIdx.x;  // float4 granules
    if (idx >= 802816) return;
    int xq = idx % 14;
    int y = (idx / 14) % 56;
    int g = (idx / (14 * 56)) % 32;
    int n = idx / (14 * 56 * 32);
    float sx = 0.f, sy = 0.f, sz = 0.f, sw = 0.f;
    float scale = p2w[g];
#pragma unroll
    for (int k = 0; k < 3; ++k) {
        int yy = y + 3 * k - 3;
        if (yy < 0 || yy >= 56) continue;
        float w = w5[g * 3 + k] * scale;
        const float4 v = *(const float4*)(t1 + ((size_t)(n * 32 + g) * 56 + yy) * 56 + xq * 4);
        sx += v.x * w; sy += v.y * w; sz += v.z * w; sw += v.w * w;
    }
    float4 s = {sx, sy, sz, sw};
    *(float4*)(t5 + (size_t)idx * 4) = s;
}

// ---------------- pool: t4 -> t11 ----------------
__global__ void k_pool(const float* __restrict__ t4, float* __restrict__ t11) {
    int by = blockIdx.x;
    int n = by / 56, y = by % 56;
    int px = threadIdx.x;
    if (px >= 56) return;
    float s = 0.f;
    for (int j = 0; j < 7; ++j) {
        int xx = px + 3 * j - 9;
        bool xin = (xx >= 0 && xx < 56);
        for (int dy = -1; dy <= 1; ++dy) {
            int yc = y + dy;
            if (yc < 0 || yc >= 56) continue;
            float m = -3.4e38f;
            for (int i = 0; i < 7; ++i) {
                int yy = yc + 3 * i - 9;
                float v = (xin && yy >= 0 && yy < 56) ? t4[(size_t)(n * 56 + yy) * 56 + xx] : 0.f;
                m = fmaxf(m, v);
            }
            s += fmaxf(m, 0.f);
        }
    }
    t11[(size_t)(n * 56 + y) * 56 + px] = s * (1.f / 21.f);
}

// ---------------- t14: 3x3 conv on t11 ----------------
__global__ void k_t14(const float* __restrict__ t11, const float* __restrict__ w14,
                      float* __restrict__ t14) {
    int by = blockIdx.x;
    int n = by / 56, y = by % 56;
    int px = threadIdx.x;
    if (px >= 56) return;
    float s = 0.f;
#pragma unroll
    for (int dy = 0; dy < 3; ++dy) {
        int yy = y + dy - 1;
        if (yy < 0 || yy >= 56) continue;
#pragma unroll
        for (int dx = 0; dx < 3; ++dx) {
            int xx = px + dx - 1;
            if (xx < 0 || xx >= 56) continue;
            s += t11[(size_t)(n * 56 + yy) * 56 + xx] * w14[dy * 3 + dx];
        }
    }
    t14[(size_t)(n * 56 + y) * 56 + px] = s;
}

// ---------------- t8: conv 32->32, 7 w-taps dil 2 -> t8T (transposed+swizzled bf16) ----
// t8T row (n,y): 70 pos x 32 ci bf16 (4480 B); unit (pos,g): off = pos*64 + ((g^((pos>>1)&3))<<4).
__global__ __launch_bounds__(256) void k_t8(const float* __restrict__ t5,
                                            const float* __restrict__ w8,
                                            char* __restrict__ t8T) {
    int by = blockIdx.x;  // 448
    int n = by / 14;
    int y = (by % 14) * 4 + (threadIdx.x >> 6);
    int u = threadIdx.x & 63;
    int co0 = (u >> 3) * 4;
    int px0 = (u & 7) * 7;
    float acc[4][7] = {};
    for (int ci = 0; ci < 32; ++ci) {
        const float* r = t5 + ((size_t)(n * 32 + ci) * 56 + y) * 56;
        float seg[19];
#pragma unroll
        for (int t = 0; t < 19; ++t) {
            int p = px0 - 6 + t;
            seg[t] = (p >= 0 && p < 56) ? r[p] : 0.f;
        }
#pragma unroll
        for (int j = 0; j < 7; ++j) {
            float wv[4];
#pragma unroll
            for (int qq = 0; qq < 4; ++qq) wv[qq] = w8[(co0 + qq) * 224 + ci * 7 + j];
#pragma unroll
            for (int qq = 0; qq < 4; ++qq)
#pragma unroll
                for (int p = 0; p < 7; ++p)
                    acc[qq][p] += seg[p + 2 * j] * wv[qq];
        }
    }
    char* rowo = t8T + (size_t)(n * 56 + y) * 4480;
#pragma unroll
    for (int qq = 0; qq < 4; ++qq) {
        int co = co0 + qq;
        int gsl = (co >> 3);
        int lo = (co & 7) * 2;
#pragma unroll
        for (int p = 0; p < 7; ++p) {
            int pos = px0 + p + 3;
            __hip_bfloat16 bv = __float2bfloat16(acc[qq][p]);
            *(unsigned short*)(rowo + pos * 64 + ((gsl ^ ((pos >> 1) & 3)) << 4) + lo) =
                *(unsigned short*)&bv;
        }
        if ((u & 7) == 0) {
#pragma unroll
            for (int pos = 0; pos < 3; ++pos)
                *(unsigned short*)(rowo + pos * 64 + ((gsl ^ ((pos >> 1) & 3)) << 4) + lo) = 0;
        }
        if ((u & 7) == 7) {
#pragma unroll
            for (int pos = 59; pos < 70; ++pos)
                *(unsigned short*)(rowo + pos * 64 + ((gsl ^ ((pos >> 1) & 3)) << 4) + lo) = 0;
        }
    }
}

// ---------------- MFMA fused kernel: t8T -> t15 -> t16 + t14 -> out ----------------
// grid 1792, block 256 (4 waves). B staged once (linear copy, pre-swizzled);
// A-frags direct from L2; barrier-free K-loop.
__global__ __launch_bounds__(256) void k_t15m(const char* __restrict__ t8T,
                                              const unsigned short* __restrict__ Wfb,
                                              const float* __restrict__ w16,
                                              const float* __restrict__ t14,
                                              float* __restrict__ out) {
    __shared__ __align__(16) char lds[33792];
    const int t = threadIdx.x;
    const int by = blockIdx.x;
    const int n = by / 56, y = by % 56;
    const int l = t & 63, h = l >> 4, q = l & 15;
    const int co0 = (t >> 6) * 64;

    // ---- stage valid dy rows: linear 16B copies ----
    for (int dy = 0; dy < 3; ++dy) {
        int yy = y + 2 * dy - 2;
        if (yy < 0 || yy >= 56) continue;
        const char* src = t8T + (size_t)(n * 56 + yy) * 4480;
        for (int u = t; u < 280; u += 256)
            *reinterpret_cast<s8v*>(lds + dy * 4480 + u * 16) =
                *reinterpret_cast<const s8v*>(src + u * 16);
    }
    __syncthreads();

    f32x4 acc[4][4];
#pragma unroll
    for (int m = 0; m < 4; ++m)
#pragma unroll
        for (int nt = 0; nt < 4; ++nt)
            acc[m][nt] = (f32x4)0.f;

    for (int dy = 0; dy < 3; ++dy) {
        int yy = y + 2 * dy - 2;
        if (yy < 0 || yy >= 56) continue;   // block-uniform
        for (int dx = 0; dx < 7; ++dx) {
            int kk = dy * 7 + dx;
            s8v af[4];
#pragma unroll
            for (int m = 0; m < 4; ++m)
                af[m] = *reinterpret_cast<const s8v*>(
                    Wfb + (size_t)kk * 8192 + (co0 + m * 16 + q) * 32 + h * 8);
#pragma unroll
            for (int nt = 0; nt < 4; ++nt) {
                int xp = nt * 16 + q + dx;
                s8v bf = *reinterpret_cast<const s8v*>(
                    lds + dy * 4480 + xp * 64 + ((h ^ ((xp >> 1) & 3)) << 4));
#pragma unroll
                for (int m = 0; m < 4; ++m)
                    acc[m][nt] =
                        __builtin_amdgcn_mfma_f32_16x16x32_bf16(af[m], bf, acc[m][nt], 0, 0, 0);
            }
        }
    }

    __syncthreads();
    // ---- rowbuf [co 256][x 66] bf16 (reuses LDS) ----
#pragma unroll
    for (int m = 0; m < 4; ++m)
#pragma unroll
        for (int nt = 0; nt < 4; ++nt)
#pragma unroll
            for (int r = 0; r < 4; ++r) {
                int co = co0 + m * 16 + h * 4 + r;
                int xx = nt * 16 + q;
                *reinterpret_cast<__hip_bfloat16*>(lds + (co * 66 + xx) * 2) =
                    __float2bfloat16(acc[m][nt][r]);
            }
    __syncthreads();

    // ---- t16 (depthwise, 3 taps dil 3) + t14 -> out ----
    int xg = t & 7;
    float t14v[7];
    const float* t14r = t14 + (size_t)(n * 56 + y) * 56;
#pragma unroll
    for (int p = 0; p < 7; ++p) t14v[p] = t14r[xg * 7 + p];
    for (int cb = 0; cb < 256; cb += 32) {
        int co = cb + (t >> 3);
        float wa = w16[co * 3], wb = w16[co * 3 + 1], wc = w16[co * 3 + 2];
        float* orow = out + ((size_t)(n * 256 + co) * 56 + y) * 56;
#pragma unroll
        for (int p = 0; p < 7; ++p) {
            int xx = xg * 7 + p;
            float s = __bfloat162float(*reinterpret_cast<const __hip_bfloat16*>(
                          lds + (co * 66 + xx) * 2)) * wb + t14v[p];
            if (xx >= 3)
                s += __bfloat162float(*reinterpret_cast<const __hip_bfloat16*>(
                         lds + (co * 66 + xx - 3) * 2)) * wa;
            if (xx <= 52)
                s += __bfloat162float(*reinterpret_cast<const __hip_bfloat16*>(
                         lds + (co * 66 + xx + 3) * 2)) * wc;
            orow[xx] = s;
        }
    }
}

extern "C" void kernel_launch(void* const* d_in, const int* in_sizes, int n_in,
                              void* d_out, int out_size, void* d_ws, size_t ws_size,
                              hipStream_t stream) {
    const float* x   = (const float*)d_in[0];
    const float* w1  = (const float*)d_in[1];
    const float* p2w = (const float*)d_in[2];
    const float* w3  = (const float*)d_in[3];
    const float* w4  = (const float*)d_in[4];
    const float* w5  = (const float*)d_in[5];
    const float* w8  = (const float*)d_in[6];
    const float* w12 = (const float*)d_in[7];
    const float* w14 = (const float*)d_in[8];
    const float* w15 = (const float*)d_in[9];
    const float* w16 = (const float*)d_in[10];
    float* out = (float*)d_out;

    float* ws = (float*)d_ws;
    float* t1   = ws;                  // 3211264 f32; t8T aliases it after t1 is dead
    float* t5   = t1 + 3211264;        // 3211264 f32
    float* t4   = t5 + 3211264;        // 100352
    float* t11  = t4 + 100352;         // 100352
    float* t14v = t11 + 100352;        // 100352
    float* W34  = t14v + 100352;       // 288
    __hip_bfloat16* Wfb = (__hip_bfloat16*)(W34 + 288);   // 172032 bf16
    __hip_bfloat16* w1b = Wfb + 172032;                   // 24576 bf16
    char* t8T = (char*)t1;             // 1792*4480 = 8,028,160 B (aliased over t1)

    fuse_w34<<<5, 64, 0, stream>>>(w3, w4, W34);
    fuse_w1215b<<<672, 256, 0, stream>>>(w15, w12, Wfb);
    fuse_w1b<<<96, 256, 0, stream>>>(w1, w1b);

    k_t1f<<<1792, 256, 0, stream>>>(x, (const unsigned short*)w1b, t1);
    k_t4<<<1792, 64, 0, stream>>>(t1, W34, t4);
    k_t5<<<3136, 256, 0, stream>>>(t1, p2w, w5, t5);
    k_pool<<<1792, 64, 0, stream>>>(t4, t11);
    k_t14<<<1792, 64, 0, stream>>>(t11, w14, t14v);
    k_t8<<<448, 256, 0, stream>>>(t5, w8, t8T);
    k_t15m<<<1792, 256, 0, stream>>>(t8T, (const unsigned short*)Wfb, w16, t14v, out);
}

// Round 5
// 268.468 us; speedup vs baseline: 3.3890x; 1.3007x over previous
//
#include <hip/hip_runtime.h>
#include <hip/hip_bf16.h>
#include <cstddef>

typedef __attribute__((ext_vector_type(8))) short s8v;
typedef __attribute__((ext_vector_type(4))) float f32x4;

// ---------------- weight fusion kernels ----------------
// W34[ci][k1][k2] = sum_co w3[co,ci,k1] * w4[co,k2]   (32*3*3 = 288)
__global__ void fuse_w34(const float* __restrict__ w3, const float* __restrict__ w4,
                         float* __restrict__ W34) {
    int idx = blockIdx.x * blockDim.x + threadIdx.x;
    if (idx >= 288) return;
    int ci = idx / 9, k1 = (idx / 3) % 3, k2 = idx % 3;
    float s = 0.f;
    for (int co = 0; co < 256; ++co)
        s += w3[(co * 32 + ci) * 3 + k1] * w4[co * 3 + k2];
    W34[idx] = s;
}

// Wfb[kk][co][ci] (bf16), kk = dy*7+dx:  sum_m w15[o,3m+dy] * w12[m,ci,dx]
__global__ void fuse_w1215b(const float* __restrict__ w15, const float* __restrict__ w12,
                            __hip_bfloat16* __restrict__ Wfb) {
    int idx = blockIdx.x * blockDim.x + threadIdx.x;
    if (idx >= 21 * 256 * 32) return;
    int ci = idx & 31, co = (idx >> 5) & 255, kk = idx >> 13;
    int dy = kk / 7, dx = kk % 7;
    float s = 0.f;
    for (int m = 0; m < 256; ++m)
        s += w15[co * 768 + m * 3 + dy] * w12[(m * 32 + ci) * 7 + dx];
    Wfb[idx] = __float2bfloat16(s);
}

// w1b[k][c][h][co][j]: bf16 repack of w1 (co,ci,k), ci = c*32+h*8+j.
__global__ void fuse_w1b(const float* __restrict__ w1, __hip_bfloat16* __restrict__ w1b) {
    int idx = blockIdx.x * blockDim.x + threadIdx.x;
    if (idx >= 24576) return;
    int j = idx & 7, co = (idx >> 3) & 31, h = (idx >> 8) & 3, c = (idx >> 10) & 7, k = idx >> 13;
    int ci = c * 32 + h * 8 + j;
    w1b[idx] = __float2bfloat16(w1[(co * 256 + ci) * 3 + k]);
}

// w8b[j][h][co][jj]: bf16 repack of w8 (co,ci,j), ci = h*8+jj.  7*4*32*8 = 7168
__global__ void fuse_w8b(const float* __restrict__ w8, __hip_bfloat16* __restrict__ w8b) {
    int idx = blockIdx.x * blockDim.x + threadIdx.x;
    if (idx >= 7168) return;
    int jj = idx & 7, co = (idx >> 3) & 31, h = (idx >> 8) & 3, j = idx >> 10;
    w8b[idx] = __float2bfloat16(w8[co * 224 + (h * 8 + jj) * 7 + j]);
}

// ---------------- t1 fused MFMA: conv 256->32, 3 w-taps dil 3 ----------------
// grid 1792 (n,y), block 256 = 4 waves. Coalesced float4 x-reads -> bf16 LDS
// transpose tile [70 pos][32 g(8ci)], slot = g ^ (pos&15). Wave-split K, LDS
// reduce, wave0 stores.
__global__ __launch_bounds__(256) void k_t1f(const float* __restrict__ x,
                                             const unsigned short* __restrict__ w1b,
                                             float* __restrict__ t1) {
    __shared__ __align__(16) char lds[36864];
    const int t = threadIdx.x, b = blockIdx.x;
    const int n = b / 56, y = b % 56;
    const int w = t >> 6, l = t & 63, h = l >> 4, q = l & 15;
    const float* xr = x + (size_t)(n * 256) * 3136 + y * 56;  // + ci*3136 + xx

    // ---- halo zeros: pos {0,1,2,59..69} x 32 g = 448 units ----
#pragma unroll
    for (int it = 0; it < 2; ++it) {
        int u = it * 256 + t;
        if (u < 448) {
            int pi = u >> 5, g = u & 31;
            int pos = (pi < 3) ? pi : (56 + pi);
            *reinterpret_cast<s8v*>(lds + pos * 512 + ((g ^ (pos & 15)) << 4)) = (s8v)0;
        }
    }
    // ---- coalesced stage: 3584 float4 units (ci, xq) ----
#pragma unroll 2
    for (int it = 0; it < 14; ++it) {
        int u = it * 256 + t;
        int ci = u / 14, xq = u % 14;
        float4 v = *(const float4*)(xr + (size_t)ci * 3136 + xq * 4);
        int g = ci >> 3, lo = (ci & 7) * 2;
#pragma unroll
        for (int j = 0; j < 4; ++j) {
            int pos = xq * 4 + j + 3;
            __hip_bfloat16 bv = __float2bfloat16(((const float*)&v)[j]);
            *(unsigned short*)(lds + pos * 512 + ((g ^ (pos & 15)) << 4) + lo) =
                *(unsigned short*)&bv;
        }
    }
    __syncthreads();

    f32x4 acc[2][4];
#pragma unroll
    for (int m = 0; m < 2; ++m)
#pragma unroll
        for (int nt = 0; nt < 4; ++nt) acc[m][nt] = (f32x4)0.f;

    // ---- K-loop: wave w handles ci-chunks {2w, 2w+1}; no barriers ----
    for (int cc = 0; cc < 2; ++cc) {
        const int c = 2 * w + cc;
        const int g = c * 4 + h;
#pragma unroll
        for (int k = 0; k < 3; ++k) {
            s8v af[2];
#pragma unroll
            for (int m = 0; m < 2; ++m)
                af[m] = *reinterpret_cast<const s8v*>(
                    w1b + (size_t)((((k * 8 + c) * 4 + h) * 32 + m * 16 + q) * 8));
#pragma unroll
            for (int nt = 0; nt < 4; ++nt) {
                int pos = nt * 16 + q + 3 * k;
                s8v bf = *reinterpret_cast<const s8v*>(lds + pos * 512 + ((g ^ (pos & 15)) << 4));
                acc[0][nt] = __builtin_amdgcn_mfma_f32_16x16x32_bf16(af[0], bf, acc[0][nt], 0, 0, 0);
                acc[1][nt] = __builtin_amdgcn_mfma_f32_16x16x32_bf16(af[1], bf, acc[1][nt], 0, 0, 0);
            }
        }
    }

    // ---- reduce 4 partial K-sums via LDS, wave 0 stores ----
    __syncthreads();
    if (w > 0) {
#pragma unroll
        for (int m = 0; m < 2; ++m)
#pragma unroll
            for (int nt = 0; nt < 4; ++nt)
                *reinterpret_cast<f32x4*>(lds + (((w - 1) * 8 + m * 4 + nt) * 64 + l) * 16) =
                    acc[m][nt];
    }
    __syncthreads();
    if (w == 0) {
#pragma unroll
        for (int m = 0; m < 2; ++m)
#pragma unroll
            for (int nt = 0; nt < 4; ++nt) {
                f32x4 a = acc[m][nt];
#pragma unroll
                for (int s = 0; s < 3; ++s)
                    a += *reinterpret_cast<const f32x4*>(
                        lds + ((s * 8 + m * 4 + nt) * 64 + l) * 16);
                int px = nt * 16 + q;
                if (px < 56) {
#pragma unroll
                    for (int r = 0; r < 4; ++r)
                        t1[((size_t)(n * 32 + m * 16 + h * 4 + r) * 56 + y) * 56 + px] = a[r];
                }
            }
    }
}

// ---------------- t4: 32ch, 3x3 taps dil (2,3), via W34 ----------------
__global__ void k_t4(const float* __restrict__ t1, const float* __restrict__ W34,
                     float* __restrict__ t4) {
    int by = blockIdx.x;  // N*H
    int n = by / 56, y = by % 56;
    int px = threadIdx.x;
    if (px >= 56) return;
    float acc = 0.f;
    for (int ci = 0; ci < 32; ++ci) {
#pragma unroll
        for (int k1 = 0; k1 < 3; ++k1) {
            int yy = y + 2 * k1 - 2;
            if (yy < 0 || yy >= 56) continue;
            const float* r = t1 + ((size_t)(n * 32 + ci) * 56 + yy) * 56;
#pragma unroll
            for (int k2 = 0; k2 < 3; ++k2) {
                int xx = px + 3 * k2 - 3;
                if (xx >= 0 && xx < 56)
                    acc += r[xx] * W34[ci * 9 + k1 * 3 + k2];
            }
        }
    }
    t4[(size_t)(n * 56 + y) * 56 + px] = acc;
}

// ---------------- pool: t4 -> t11 ----------------
__global__ void k_pool(const float* __restrict__ t4, float* __restrict__ t11) {
    int by = blockIdx.x;
    int n = by / 56, y = by % 56;
    int px = threadIdx.x;
    if (px >= 56) return;
    float s = 0.f;
    for (int j = 0; j < 7; ++j) {
        int xx = px + 3 * j - 9;
        bool xin = (xx >= 0 && xx < 56);
        for (int dy = -1; dy <= 1; ++dy) {
            int yc = y + dy;
            if (yc < 0 || yc >= 56) continue;
            float m = -3.4e38f;
            for (int i = 0; i < 7; ++i) {
                int yy = yc + 3 * i - 9;
                float v = (xin && yy >= 0 && yy < 56) ? t4[(size_t)(n * 56 + yy) * 56 + xx] : 0.f;
                m = fmaxf(m, v);
            }
            s += fmaxf(m, 0.f);
        }
    }
    t11[(size_t)(n * 56 + y) * 56 + px] = s * (1.f / 21.f);
}

// ---------------- t14: 3x3 conv on t11 ----------------
__global__ void k_t14(const float* __restrict__ t11, const float* __restrict__ w14,
                      float* __restrict__ t14) {
    int by = blockIdx.x;
    int n = by / 56, y = by % 56;
    int px = threadIdx.x;
    if (px >= 56) return;
    float s = 0.f;
#pragma unroll
    for (int dy = 0; dy < 3; ++dy) {
        int yy = y + dy - 1;
        if (yy < 0 || yy >= 56) continue;
#pragma unroll
        for (int dx = 0; dx < 3; ++dx) {
            int xx = px + dx - 1;
            if (xx < 0 || xx >= 56) continue;
            s += t11[(size_t)(n * 56 + yy) * 56 + xx] * w14[dy * 3 + dx];
        }
    }
    t14[(size_t)(n * 56 + y) * 56 + px] = s;
}

// ---------------- fused t5+t8 MFMA -> t8T ----------------
// grid 1792 (n,y), block 256 = 4 waves. Stage: t5 row computed on the fly from
// 3 coalesced f32 t1 rows -> bf16 LDS [76 pos][32 ci] (pos = x+6), slot =
// g ^ ((pos>>1)&3). Wave w = x-quadrant; 7 taps x 2 m-frags = 14 MFMA; store
// D-frags to t8T (pos = x+3, 70-pos swizzled row) incl. halo zeros.
__global__ __launch_bounds__(256) void k_t58(const float* __restrict__ t1,
                                             const float* __restrict__ p2w,
                                             const float* __restrict__ w5,
                                             const unsigned short* __restrict__ w8b,
                                             char* __restrict__ t8T) {
    __shared__ __align__(16) char lds[4864];  // 76*64
    const int t = threadIdx.x, b = blockIdx.x;
    const int n = b / 56, y = b % 56;
    const int w = t >> 6, l = t & 63, h = l >> 4, q = l & 15;
    const float* t1b = t1 + (size_t)(n * 32) * 3136;

    // halo zeros: pos {0..5, 62..75} x 4 g = 80 units
    if (t < 80) {
        int ph = t >> 2, g = t & 3;
        int pos = (ph < 6) ? ph : (56 + ph);
        *reinterpret_cast<s8v*>(lds + pos * 64 + ((g ^ ((pos >> 1) & 3)) << 4)) = (s8v)0;
    }
    // stage: 448 units (ci, xq); t5 = p2w[ci] * sum_k w5[ci,k] * t1[ci, y+3k-3, :]
#pragma unroll
    for (int it = 0; it < 2; ++it) {
        int u = it * 256 + t;
        if (u < 448) {
            int ci = u / 14, xq = u % 14;
            float sc = p2w[ci];
            float4 s = {0.f, 0.f, 0.f, 0.f};
#pragma unroll
            for (int k = 0; k < 3; ++k) {
                int yy = y + 3 * k - 3;
                if (yy < 0 || yy >= 56) continue;
                float wv = w5[ci * 3 + k] * sc;
                float4 v = *(const float4*)(t1b + (size_t)ci * 3136 + yy * 56 + xq * 4);
                s.x += wv * v.x; s.y += wv * v.y; s.z += wv * v.z; s.w += wv * v.w;
            }
            int g = ci >> 3, lo = (ci & 7) * 2;
#pragma unroll
            for (int j = 0; j < 4; ++j) {
                int pos = xq * 4 + j + 6;
                __hip_bfloat16 bv = __float2bfloat16(((const float*)&s)[j]);
                *(unsigned short*)(lds + pos * 64 + ((g ^ ((pos >> 1) & 3)) << 4) + lo) =
                    *(unsigned short*)&bv;
            }
        }
    }
    __syncthreads();

    f32x4 acc[2];
    acc[0] = (f32x4)0.f; acc[1] = (f32x4)0.f;
#pragma unroll
    for (int j = 0; j < 7; ++j) {
        s8v af[2];
#pragma unroll
        for (int m = 0; m < 2; ++m)
            af[m] = *reinterpret_cast<const s8v*>(
                w8b + (size_t)(((j * 4 + h) * 32 + m * 16 + q) * 8));
        int pos = w * 16 + q + 2 * j;
        s8v bf = *reinterpret_cast<const s8v*>(lds + pos * 64 + ((h ^ ((pos >> 1) & 3)) << 4));
        acc[0] = __builtin_amdgcn_mfma_f32_16x16x32_bf16(af[0], bf, acc[0], 0, 0, 0);
        acc[1] = __builtin_amdgcn_mfma_f32_16x16x32_bf16(af[1], bf, acc[1], 0, 0, 0);
    }

    // store to t8T row (pos = x+3, slot = g ^ ((pos>>1)&3))
    char* rowo = t8T + (size_t)(n * 56 + y) * 4480;
    if (t < 56) {  // halo: pos {0,1,2,59..69} x 4 g
        int ph = t >> 2, g = t & 3;
        int pos = (ph < 3) ? ph : (56 + ph);
        *reinterpret_cast<s8v*>(rowo + pos * 64 + ((g ^ ((pos >> 1) & 3)) << 4)) = (s8v)0;
    }
    int xx = w * 16 + q;
    if (xx < 56) {
        int pos = xx + 3;
#pragma unroll
        for (int m = 0; m < 2; ++m) {
#pragma unroll
            for (int r = 0; r < 4; ++r) {
                int co = m * 16 + h * 4 + r;
                __hip_bfloat16 bv = __float2bfloat16(acc[m][r]);
                *(unsigned short*)(rowo + pos * 64 + (((co >> 3) ^ ((pos >> 1) & 3)) << 4) +
                                   (co & 7) * 2) = *(unsigned short*)&bv;
            }
        }
    }
}

// ---------------- MFMA fused kernel: t8T -> t15 -> t16 + t14 -> out ----------------
// grid 896 (n, y0=2*(b%28)), block 512 = 8 waves. Waves 0-3: row y0, waves 4-7:
// row y0+1 (halves Wfb L2 traffic). B staged linearly (6 t8T rows); barrier-free
// K-loop; bf16 rowbuf epilogue with t16+t14.
__global__ __launch_bounds__(512) void k_t15m2(const char* __restrict__ t8T,
                                               const unsigned short* __restrict__ Wfb,
                                               const float* __restrict__ w16,
                                               const float* __restrict__ t14,
                                               float* __restrict__ out) {
    __shared__ __align__(16) char lds[67584];
    const int t = threadIdx.x;
    const int b = blockIdx.x;
    const int n = b / 28, y0 = (b % 28) * 2;
    const int l = t & 63, h = l >> 4, q = l & 15;
    const int w = t >> 6;
    const int rg = w >> 2;           // row group (0/1)
    const int y = y0 + rg;
    const int co0 = (w & 3) * 64;

    // ---- stage 6 rows of t8T (linear 16B copies) ----
    for (int e = t; e < 1680; e += 512) {
        int ridx = e / 280, u = e - ridx * 280;
        int yy = y0 - 2 + ridx;
        if (yy < 0 || yy >= 56) continue;
        *reinterpret_cast<s8v*>(lds + ridx * 4480 + u * 16) =
            *reinterpret_cast<const s8v*>(t8T + (size_t)(n * 56 + yy) * 4480 + u * 16);
    }
    __syncthreads();

    f32x4 acc[4][4];
#pragma unroll
    for (int m = 0; m < 4; ++m)
#pragma unroll
        for (int nt = 0; nt < 4; ++nt)
            acc[m][nt] = (f32x4)0.f;

    for (int dy = 0; dy < 3; ++dy) {
        int yy = y + 2 * dy - 2;
        if (yy < 0 || yy >= 56) continue;   // wave-uniform
        int ridx = rg + 2 * dy;
        for (int dx = 0; dx < 7; ++dx) {
            int kk = dy * 7 + dx;
            s8v af[4];
#pragma unroll
            for (int m = 0; m < 4; ++m)
                af[m] = *reinterpret_cast<const s8v*>(
                    Wfb + (size_t)kk * 8192 + (co0 + m * 16 + q) * 32 + h * 8);
#pragma unroll
            for (int nt = 0; nt < 4; ++nt) {
                int xp = nt * 16 + q + dx;
                s8v bf = *reinterpret_cast<const s8v*>(
                    lds + ridx * 4480 + xp * 64 + ((h ^ ((xp >> 1) & 3)) << 4));
#pragma unroll
                for (int m = 0; m < 4; ++m)
                    acc[m][nt] =
                        __builtin_amdgcn_mfma_f32_16x16x32_bf16(af[m], bf, acc[m][nt], 0, 0, 0);
            }
        }
    }

    __syncthreads();
    // ---- rowbuf [2 rows][co 256][x 66] bf16 (reuses LDS) ----
    {
        char* rb = lds + rg * 33792;
#pragma unroll
        for (int m = 0; m < 4; ++m)
#pragma unroll
            for (int nt = 0; nt < 4; ++nt)
#pragma unroll
                for (int r = 0; r < 4; ++r) {
                    int co = co0 + m * 16 + h * 4 + r;
                    int xx = nt * 16 + q;
                    *reinterpret_cast<__hip_bfloat16*>(rb + (co * 66 + xx) * 2) =
                        __float2bfloat16(acc[m][nt][r]);
                }
    }
    __syncthreads();

    // ---- t16 (depthwise, 3 taps dil 3) + t14 -> out ----
    const int tt = t & 255;
    const char* rb = lds + rg * 33792;
    int xg = tt & 7;
    float t14v[7];
    const float* t14r = t14 + (size_t)(n * 56 + y) * 56;
#pragma unroll
    for (int p = 0; p < 7; ++p) t14v[p] = t14r[xg * 7 + p];
    for (int cb = 0; cb < 256; cb += 32) {
        int co = cb + (tt >> 3);
        float wa = w16[co * 3], wb = w16[co * 3 + 1], wc = w16[co * 3 + 2];
        float* orow = out + ((size_t)(n * 256 + co) * 56 + y) * 56;
#pragma unroll
        for (int p = 0; p < 7; ++p) {
            int xx = xg * 7 + p;
            float s = __bfloat162float(*reinterpret_cast<const __hip_bfloat16*>(
                          rb + (co * 66 + xx) * 2)) * wb + t14v[p];
            if (xx >= 3)
                s += __bfloat162float(*reinterpret_cast<const __hip_bfloat16*>(
                         rb + (co * 66 + xx - 3) * 2)) * wa;
            if (xx <= 52)
                s += __bfloat162float(*reinterpret_cast<const __hip_bfloat16*>(
                         rb + (co * 66 + xx + 3) * 2)) * wc;
            orow[xx] = s;
        }
    }
}

extern "C" void kernel_launch(void* const* d_in, const int* in_sizes, int n_in,
                              void* d_out, int out_size, void* d_ws, size_t ws_size,
                              hipStream_t stream) {
    const float* x   = (const float*)d_in[0];
    const float* w1  = (const float*)d_in[1];
    const float* p2w = (const float*)d_in[2];
    const float* w3  = (const float*)d_in[3];
    const float* w4  = (const float*)d_in[4];
    const float* w5  = (const float*)d_in[5];
    const float* w8  = (const float*)d_in[6];
    const float* w12 = (const float*)d_in[7];
    const float* w14 = (const float*)d_in[8];
    const float* w15 = (const float*)d_in[9];
    const float* w16 = (const float*)d_in[10];
    float* out = (float*)d_out;

    float* ws = (float*)d_ws;
    float* t1   = ws;                  // 3211264 f32
    char*  t8T  = (char*)(t1 + 3211264);  // 8,028,160 B (old t5 slot; t5 eliminated)
    float* t4   = t1 + 2 * 3211264;    // 100352
    float* t11  = t4 + 100352;         // 100352
    float* t14v = t11 + 100352;        // 100352
    float* W34  = t14v + 100352;       // 288
    __hip_bfloat16* Wfb = (__hip_bfloat16*)(W34 + 288);   // 172032 bf16
    __hip_bfloat16* w1b = Wfb + 172032;                   // 24576 bf16
    __hip_bfloat16* w8b = w1b + 24576;                    // 7168 bf16

    fuse_w34<<<5, 64, 0, stream>>>(w3, w4, W34);
    fuse_w1215b<<<672, 256, 0, stream>>>(w15, w12, Wfb);
    fuse_w1b<<<96, 256, 0, stream>>>(w1, w1b);
    fuse_w8b<<<28, 256, 0, stream>>>(w8, w8b);

    k_t1f<<<1792, 256, 0, stream>>>(x, (const unsigned short*)w1b, t1);
    k_t4<<<1792, 64, 0, stream>>>(t1, W34, t4);
    k_pool<<<1792, 64, 0, stream>>>(t4, t11);
    k_t14<<<1792, 64, 0, stream>>>(t11, w14, t14v);
    k_t58<<<1792, 256, 0, stream>>>(t1, p2w, w5, (const unsigned short*)w8b, t8T);
    k_t15m2<<<896, 512, 0, stream>>>(t8T, (const unsigned short*)Wfb, w16, t14v, out);
}

// Round 6
// 228.008 us; speedup vs baseline: 3.9904x; 1.1774x over previous
//
#include <hip/hip_runtime.h>
#include <hip/hip_bf16.h>
#include <cstddef>

typedef __attribute__((ext_vector_type(8))) short s8v;
typedef __attribute__((ext_vector_type(4))) float f32x4;

// ---------------- weight fusion kernels ----------------
// W34[ci][k1][k2] = sum_co w3[co,ci,k1] * w4[co,k2]   (32*3*3 = 288)
__global__ void fuse_w34(const float* __restrict__ w3, const float* __restrict__ w4,
                         float* __restrict__ W34) {
    int idx = blockIdx.x * blockDim.x + threadIdx.x;
    if (idx >= 288) return;
    int ci = idx / 9, k1 = (idx / 3) % 3, k2 = idx % 3;
    float s = 0.f;
    for (int co = 0; co < 256; ++co)
        s += w3[(co * 32 + ci) * 3 + k1] * w4[co * 3 + k2];
    W34[idx] = s;
}

// Wfb[kk][co][ci] (bf16), kk = dy*7+dx:  sum_m w15[o,3m+dy] * w12[m,ci,dx]
__global__ void fuse_w1215b(const float* __restrict__ w15, const float* __restrict__ w12,
                            __hip_bfloat16* __restrict__ Wfb) {
    int idx = blockIdx.x * blockDim.x + threadIdx.x;
    if (idx >= 21 * 256 * 32) return;
    int ci = idx & 31, co = (idx >> 5) & 255, kk = idx >> 13;
    int dy = kk / 7, dx = kk % 7;
    float s = 0.f;
    for (int m = 0; m < 256; ++m)
        s += w15[co * 768 + m * 3 + dy] * w12[(m * 32 + ci) * 7 + dx];
    Wfb[idx] = __float2bfloat16(s);
}

// w1b[k][c][h][co][j]: bf16 repack of w1 (co,ci,k), ci = c*32+h*8+j.
__global__ void fuse_w1b(const float* __restrict__ w1, __hip_bfloat16* __restrict__ w1b) {
    int idx = blockIdx.x * blockDim.x + threadIdx.x;
    if (idx >= 24576) return;
    int j = idx & 7, co = (idx >> 3) & 31, h = (idx >> 8) & 3, c = (idx >> 10) & 7, k = idx >> 13;
    int ci = c * 32 + h * 8 + j;
    w1b[idx] = __float2bfloat16(w1[(co * 256 + ci) * 3 + k]);
}

// w8b[j][h][co][jj]: bf16 repack of w8 (co,ci,j), ci = h*8+jj.  7*4*32*8 = 7168
__global__ void fuse_w8b(const float* __restrict__ w8, __hip_bfloat16* __restrict__ w8b) {
    int idx = blockIdx.x * blockDim.x + threadIdx.x;
    if (idx >= 7168) return;
    int jj = idx & 7, co = (idx >> 3) & 31, h = (idx >> 8) & 3, j = idx >> 10;
    w8b[idx] = __float2bfloat16(w8[co * 224 + (h * 8 + jj) * 7 + j]);
}

// ---------------- t1 fused MFMA: conv 256->32, 3 w-taps dil 3 ----------------
// grid 1792 (n,y), block 256 = 4 waves. Coalesced float4 x-reads -> bf16 LDS
// transpose tile [70 pos][32 g(8ci)], slot = g ^ (pos&15). Wave-split K, LDS
// reduce, wave0 stores.
__global__ __launch_bounds__(256) void k_t1f(const float* __restrict__ x,
                                             const unsigned short* __restrict__ w1b,
                                             float* __restrict__ t1) {
    __shared__ __align__(16) char lds[36864];
    const int t = threadIdx.x, b = blockIdx.x;
    const int n = b / 56, y = b % 56;
    const int w = t >> 6, l = t & 63, h = l >> 4, q = l & 15;
    const float* xr = x + (size_t)(n * 256) * 3136 + y * 56;  // + ci*3136 + xx

    // ---- halo zeros: pos {0,1,2,59..69} x 32 g = 448 units ----
#pragma unroll
    for (int it = 0; it < 2; ++it) {
        int u = it * 256 + t;
        if (u < 448) {
            int pi = u >> 5, g = u & 31;
            int pos = (pi < 3) ? pi : (56 + pi);
            *reinterpret_cast<s8v*>(lds + pos * 512 + ((g ^ (pos & 15)) << 4)) = (s8v)0;
        }
    }
    // ---- coalesced stage: 3584 float4 units (ci, xq) ----
#pragma unroll 2
    for (int it = 0; it < 14; ++it) {
        int u = it * 256 + t;
        int ci = u / 14, xq = u % 14;
        float4 v = *(const float4*)(xr + (size_t)ci * 3136 + xq * 4);
        int g = ci >> 3, lo = (ci & 7) * 2;
#pragma unroll
        for (int j = 0; j < 4; ++j) {
            int pos = xq * 4 + j + 3;
            __hip_bfloat16 bv = __float2bfloat16(((const float*)&v)[j]);
            *(unsigned short*)(lds + pos * 512 + ((g ^ (pos & 15)) << 4) + lo) =
                *(unsigned short*)&bv;
        }
    }
    __syncthreads();

    f32x4 acc[2][4];
#pragma unroll
    for (int m = 0; m < 2; ++m)
#pragma unroll
        for (int nt = 0; nt < 4; ++nt) acc[m][nt] = (f32x4)0.f;

    // ---- K-loop: wave w handles ci-chunks {2w, 2w+1}; no barriers ----
    for (int cc = 0; cc < 2; ++cc) {
        const int c = 2 * w + cc;
        const int g = c * 4 + h;
#pragma unroll
        for (int k = 0; k < 3; ++k) {
            s8v af[2];
#pragma unroll
            for (int m = 0; m < 2; ++m)
                af[m] = *reinterpret_cast<const s8v*>(
                    w1b + (size_t)((((k * 8 + c) * 4 + h) * 32 + m * 16 + q) * 8));
#pragma unroll
            for (int nt = 0; nt < 4; ++nt) {
                int pos = nt * 16 + q + 3 * k;
                s8v bf = *reinterpret_cast<const s8v*>(lds + pos * 512 + ((g ^ (pos & 15)) << 4));
                acc[0][nt] = __builtin_amdgcn_mfma_f32_16x16x32_bf16(af[0], bf, acc[0][nt], 0, 0, 0);
                acc[1][nt] = __builtin_amdgcn_mfma_f32_16x16x32_bf16(af[1], bf, acc[1][nt], 0, 0, 0);
            }
        }
    }

    // ---- reduce 4 partial K-sums via LDS, wave 0 stores ----
    __syncthreads();
    if (w > 0) {
#pragma unroll
        for (int m = 0; m < 2; ++m)
#pragma unroll
            for (int nt = 0; nt < 4; ++nt)
                *reinterpret_cast<f32x4*>(lds + (((w - 1) * 8 + m * 4 + nt) * 64 + l) * 16) =
                    acc[m][nt];
    }
    __syncthreads();
    if (w == 0) {
#pragma unroll
        for (int m = 0; m < 2; ++m)
#pragma unroll
            for (int nt = 0; nt < 4; ++nt) {
                f32x4 a = acc[m][nt];
#pragma unroll
                for (int s = 0; s < 3; ++s)
                    a += *reinterpret_cast<const f32x4*>(
                        lds + ((s * 8 + m * 4 + nt) * 64 + l) * 16);
                int px = nt * 16 + q;
                if (px < 56) {
#pragma unroll
                    for (int r = 0; r < 4; ++r)
                        t1[((size_t)(n * 32 + m * 16 + h * 4 + r) * 56 + y) * 56 + px] = a[r];
                }
            }
    }
}

// ---------------- t4: 32ch, 3x3 taps dil (2,3), via W34 ----------------
__global__ void k_t4(const float* __restrict__ t1, const float* __restrict__ W34,
                     float* __restrict__ t4) {
    int by = blockIdx.x;  // N*H
    int n = by / 56, y = by % 56;
    int px = threadIdx.x;
    if (px >= 56) return;
    float acc = 0.f;
    for (int ci = 0; ci < 32; ++ci) {
#pragma unroll
        for (int k1 = 0; k1 < 3; ++k1) {
            int yy = y + 2 * k1 - 2;
            if (yy < 0 || yy >= 56) continue;
            const float* r = t1 + ((size_t)(n * 32 + ci) * 56 + yy) * 56;
#pragma unroll
            for (int k2 = 0; k2 < 3; ++k2) {
                int xx = px + 3 * k2 - 3;
                if (xx >= 0 && xx < 56)
                    acc += r[xx] * W34[ci * 9 + k1 * 3 + k2];
            }
        }
    }
    t4[(size_t)(n * 56 + y) * 56 + px] = acc;
}

// ---------------- pool: t4 -> t11 ----------------
__global__ void k_pool(const float* __restrict__ t4, float* __restrict__ t11) {
    int by = blockIdx.x;
    int n = by / 56, y = by % 56;
    int px = threadIdx.x;
    if (px >= 56) return;
    float s = 0.f;
    for (int j = 0; j < 7; ++j) {
        int xx = px + 3 * j - 9;
        bool xin = (xx >= 0 && xx < 56);
        for (int dy = -1; dy <= 1; ++dy) {
            int yc = y + dy;
            if (yc < 0 || yc >= 56) continue;
            float m = -3.4e38f;
            for (int i = 0; i < 7; ++i) {
                int yy = yc + 3 * i - 9;
                float v = (xin && yy >= 0 && yy < 56) ? t4[(size_t)(n * 56 + yy) * 56 + xx] : 0.f;
                m = fmaxf(m, v);
            }
            s += fmaxf(m, 0.f);
        }
    }
    t11[(size_t)(n * 56 + y) * 56 + px] = s * (1.f / 21.f);
}

// ---------------- t14: 3x3 conv on t11 ----------------
__global__ void k_t14(const float* __restrict__ t11, const float* __restrict__ w14,
                      float* __restrict__ t14) {
    int by = blockIdx.x;
    int n = by / 56, y = by % 56;
    int px = threadIdx.x;
    if (px >= 56) return;
    float s = 0.f;
#pragma unroll
    for (int dy = 0; dy < 3; ++dy) {
        int yy = y + dy - 1;
        if (yy < 0 || yy >= 56) continue;
#pragma unroll
        for (int dx = 0; dx < 3; ++dx) {
            int xx = px + dx - 1;
            if (xx < 0 || xx >= 56) continue;
            s += t11[(size_t)(n * 56 + yy) * 56 + xx] * w14[dy * 3 + dx];
        }
    }
    t14[(size_t)(n * 56 + y) * 56 + px] = s;
}

// ---------------- fused t5+t8 MFMA -> t8T ----------------
__global__ __launch_bounds__(256) void k_t58(const float* __restrict__ t1,
                                             const float* __restrict__ p2w,
                                             const float* __restrict__ w5,
                                             const unsigned short* __restrict__ w8b,
                                             char* __restrict__ t8T) {
    __shared__ __align__(16) char lds[4864];  // 76*64
    const int t = threadIdx.x, b = blockIdx.x;
    const int n = b / 56, y = b % 56;
    const int w = t >> 6, l = t & 63, h = l >> 4, q = l & 15;
    const float* t1b = t1 + (size_t)(n * 32) * 3136;

    // halo zeros: pos {0..5, 62..75} x 4 g = 80 units
    if (t < 80) {
        int ph = t >> 2, g = t & 3;
        int pos = (ph < 6) ? ph : (56 + ph);
        *reinterpret_cast<s8v*>(lds + pos * 64 + ((g ^ ((pos >> 1) & 3)) << 4)) = (s8v)0;
    }
    // stage: 448 units (ci, xq); t5 = p2w[ci] * sum_k w5[ci,k] * t1[ci, y+3k-3, :]
#pragma unroll
    for (int it = 0; it < 2; ++it) {
        int u = it * 256 + t;
        if (u < 448) {
            int ci = u / 14, xq = u % 14;
            float sc = p2w[ci];
            float4 s = {0.f, 0.f, 0.f, 0.f};
#pragma unroll
            for (int k = 0; k < 3; ++k) {
                int yy = y + 3 * k - 3;
                if (yy < 0 || yy >= 56) continue;
                float wv = w5[ci * 3 + k] * sc;
                float4 v = *(const float4*)(t1b + (size_t)ci * 3136 + yy * 56 + xq * 4);
                s.x += wv * v.x; s.y += wv * v.y; s.z += wv * v.z; s.w += wv * v.w;
            }
            int g = ci >> 3, lo = (ci & 7) * 2;
#pragma unroll
            for (int j = 0; j < 4; ++j) {
                int pos = xq * 4 + j + 6;
                __hip_bfloat16 bv = __float2bfloat16(((const float*)&s)[j]);
                *(unsigned short*)(lds + pos * 64 + ((g ^ ((pos >> 1) & 3)) << 4) + lo) =
                    *(unsigned short*)&bv;
            }
        }
    }
    __syncthreads();

    f32x4 acc[2];
    acc[0] = (f32x4)0.f; acc[1] = (f32x4)0.f;
#pragma unroll
    for (int j = 0; j < 7; ++j) {
        s8v af[2];
#pragma unroll
        for (int m = 0; m < 2; ++m)
            af[m] = *reinterpret_cast<const s8v*>(
                w8b + (size_t)(((j * 4 + h) * 32 + m * 16 + q) * 8));
        int pos = w * 16 + q + 2 * j;
        s8v bf = *reinterpret_cast<const s8v*>(lds + pos * 64 + ((h ^ ((pos >> 1) & 3)) << 4));
        acc[0] = __builtin_amdgcn_mfma_f32_16x16x32_bf16(af[0], bf, acc[0], 0, 0, 0);
        acc[1] = __builtin_amdgcn_mfma_f32_16x16x32_bf16(af[1], bf, acc[1], 0, 0, 0);
    }

    // store to t8T row (pos = x+3, slot = g ^ ((pos>>1)&3))
    char* rowo = t8T + (size_t)(n * 56 + y) * 4480;
    if (t < 56) {  // halo: pos {0,1,2,59..69} x 4 g
        int ph = t >> 2, g = t & 3;
        int pos = (ph < 3) ? ph : (56 + ph);
        *reinterpret_cast<s8v*>(rowo + pos * 64 + ((g ^ ((pos >> 1) & 3)) << 4)) = (s8v)0;
    }
    int xx = w * 16 + q;
    if (xx < 56) {
        int pos = xx + 3;
#pragma unroll
        for (int m = 0; m < 2; ++m) {
#pragma unroll
            for (int r = 0; r < 4; ++r) {
                int co = m * 16 + h * 4 + r;
                __hip_bfloat16 bv = __float2bfloat16(acc[m][r]);
                *(unsigned short*)(rowo + pos * 64 + (((co >> 3) ^ ((pos >> 1) & 3)) << 4) +
                                   (co & 7) * 2) = *(unsigned short*)&bv;
            }
        }
    }
}

// ---------------- MFMA fused kernel: t8T -> t15 -> t16 + t14 -> out ----------------
// grid 1792 (n,y), block 256 = 4 waves (co-quadrants). Stage 3 t8T rows
// (13.4 KB LDS, 1 barrier); barrier-free K-loop, A-frags from L2; t16 epilogue
// in-register via __shfl x-rotations (f32, no rowbuf); coalesced f32 stores.
__global__ __launch_bounds__(256) void k_t15m3(const char* __restrict__ t8T,
                                               const unsigned short* __restrict__ Wfb,
                                               const float* __restrict__ w16,
                                               const float* __restrict__ t14,
                                               float* __restrict__ out) {
    __shared__ __align__(16) char lds[13440];
    const int t = threadIdx.x;
    const int b = blockIdx.x;
    const int n = b / 56, y = b % 56;
    const int l = t & 63, h = l >> 4, q = l & 15;
    const int co0 = (t >> 6) * 64;

    // ---- stage t8T rows y-2, y, y+2 (linear 16B copies) ----
    for (int it = 0; it < 4; ++it) {
        int e = it * 256 + t;
        if (e < 840) {
            int ridx = e / 280, u = e - ridx * 280;
            int yy = y + 2 * ridx - 2;
            if (yy >= 0 && yy < 56)
                *reinterpret_cast<s8v*>(lds + ridx * 4480 + u * 16) =
                    *reinterpret_cast<const s8v*>(t8T + (size_t)(n * 56 + yy) * 4480 + u * 16);
        }
    }
    __syncthreads();

    f32x4 acc[4][4];
#pragma unroll
    for (int m = 0; m < 4; ++m)
#pragma unroll
        for (int nt = 0; nt < 4; ++nt)
            acc[m][nt] = (f32x4)0.f;

    for (int dy = 0; dy < 3; ++dy) {
        int yy = y + 2 * dy - 2;
        if (yy < 0 || yy >= 56) continue;   // block-uniform
        for (int dx = 0; dx < 7; ++dx) {
            int kk = dy * 7 + dx;
            s8v af[4];
#pragma unroll
            for (int m = 0; m < 4; ++m)
                af[m] = *reinterpret_cast<const s8v*>(
                    Wfb + (size_t)kk * 8192 + (co0 + m * 16 + q) * 32 + h * 8);
#pragma unroll
            for (int nt = 0; nt < 4; ++nt) {
                int xp = nt * 16 + q + dx;
                s8v bf = *reinterpret_cast<const s8v*>(
                    lds + dy * 4480 + xp * 64 + ((h ^ ((xp >> 1) & 3)) << 4));
#pragma unroll
                for (int m = 0; m < 4; ++m)
                    acc[m][nt] =
                        __builtin_amdgcn_mfma_f32_16x16x32_bf16(af[m], bf, acc[m][nt], 0, 0, 0);
            }
        }
    }

    // ---- t16 + t14 epilogue: in-register x+-3 via shuffles, f32, coalesced ----
    const float* t14r = t14 + (size_t)(n * 56 + y) * 56;
    float t14v[4];
#pragma unroll
    for (int nt = 0; nt < 4; ++nt) {
        int xx = nt * 16 + q;
        t14v[nt] = (xx < 56) ? t14r[xx] : 0.f;
    }
    const int srcm = (l & 48) | ((q + 13) & 15);
    const int srcp = (l & 48) | ((q + 3) & 15);
#pragma unroll
    for (int m = 0; m < 4; ++m) {
#pragma unroll
        for (int r = 0; r < 4; ++r) {
            int co = co0 + m * 16 + h * 4 + r;
            float wa = w16[co * 3], wb = w16[co * 3 + 1], wc = w16[co * 3 + 2];
            float v[4], rm[4], rp[4];
#pragma unroll
            for (int nt = 0; nt < 4; ++nt) v[nt] = acc[m][nt][r];
#pragma unroll
            for (int nt = 0; nt < 4; ++nt) {
                rm[nt] = __shfl(v[nt], srcm, 64);
                rp[nt] = __shfl(v[nt], srcp, 64);
            }
            float* orow = out + ((size_t)(n * 256 + co) * 56 + y) * 56;
#pragma unroll
            for (int nt = 0; nt < 4; ++nt) {
                int xx = nt * 16 + q;
                float vm = (q >= 3) ? rm[nt] : (nt > 0 ? rm[nt - 1] : 0.f);
                float vp = (q < 13) ? rp[nt] : (nt < 3 ? rp[nt + 1] : 0.f);
                float s = v[nt] * wb + t14v[nt];
                s += (xx >= 3) ? vm * wa : 0.f;
                s += (xx <= 52) ? vp * wc : 0.f;
                if (xx < 56) orow[xx] = s;
            }
        }
    }
}

extern "C" void kernel_launch(void* const* d_in, const int* in_sizes, int n_in,
                              void* d_out, int out_size, void* d_ws, size_t ws_size,
                              hipStream_t stream) {
    const float* x   = (const float*)d_in[0];
    const float* w1  = (const float*)d_in[1];
    const float* p2w = (const float*)d_in[2];
    const float* w3  = (const float*)d_in[3];
    const float* w4  = (const float*)d_in[4];
    const float* w5  = (const float*)d_in[5];
    const float* w8  = (const float*)d_in[6];
    const float* w12 = (const float*)d_in[7];
    const float* w14 = (const float*)d_in[8];
    const float* w15 = (const float*)d_in[9];
    const float* w16 = (const float*)d_in[10];
    float* out = (float*)d_out;

    float* ws = (float*)d_ws;
    float* t1   = ws;                  // 3211264 f32
    char*  t8T  = (char*)(t1 + 3211264);  // 8,028,160 B
    float* t4   = t1 + 2 * 3211264;    // 100352
    float* t11  = t4 + 100352;         // 100352
    float* t14v = t11 + 100352;        // 100352
    float* W34  = t14v + 100352;       // 288
    __hip_bfloat16* Wfb = (__hip_bfloat16*)(W34 + 288);   // 172032 bf16
    __hip_bfloat16* w1b = Wfb + 172032;                   // 24576 bf16
    __hip_bfloat16* w8b = w1b + 24576;                    // 7168 bf16

    fuse_w34<<<5, 64, 0, stream>>>(w3, w4, W34);
    fuse_w1215b<<<672, 256, 0, stream>>>(w15, w12, Wfb);
    fuse_w1b<<<96, 256, 0, stream>>>(w1, w1b);
    fuse_w8b<<<28, 256, 0, stream>>>(w8, w8b);

    k_t1f<<<1792, 256, 0, stream>>>(x, (const unsigned short*)w1b, t1);
    k_t4<<<1792, 64, 0, stream>>>(t1, W34, t4);
    k_pool<<<1792, 64, 0, stream>>>(t4, t11);
    k_t14<<<1792, 64, 0, stream>>>(t11, w14, t14v);
    k_t58<<<1792, 256, 0, stream>>>(t1, p2w, w5, (const unsigned short*)w8b, t8T);
    k_t15m3<<<1792, 256, 0, stream>>>(t8T, (const unsigned short*)Wfb, w16, t14v, out);
}

// Round 7
// 223.955 us; speedup vs baseline: 4.0626x; 1.0181x over previous
//
#include <hip/hip_runtime.h>
#include <hip/hip_bf16.h>
#include <cstddef>

typedef __attribute__((ext_vector_type(8))) short s8v;
typedef __attribute__((ext_vector_type(4))) float f32x4;

// ---------------- weight fusion kernels ----------------
// W34[ci][k1][k2] = sum_co w3[co,ci,k1] * w4[co,k2]   (32*3*3 = 288)
__global__ void fuse_w34(const float* __restrict__ w3, const float* __restrict__ w4,
                         float* __restrict__ W34) {
    int idx = blockIdx.x * blockDim.x + threadIdx.x;
    if (idx >= 288) return;
    int ci = idx / 9, k1 = (idx / 3) % 3, k2 = idx % 3;
    float s = 0.f;
    for (int co = 0; co < 256; ++co)
        s += w3[(co * 32 + ci) * 3 + k1] * w4[co * 3 + k2];
    W34[idx] = s;
}

// Wfb[kk][co][ci] (bf16), kk = dy*7+dx:  sum_m w15[o,3m+dy] * w12[m,ci,dx]
__global__ void fuse_w1215b(const float* __restrict__ w15, const float* __restrict__ w12,
                            __hip_bfloat16* __restrict__ Wfb) {
    int idx = blockIdx.x * blockDim.x + threadIdx.x;
    if (idx >= 21 * 256 * 32) return;
    int ci = idx & 31, co = (idx >> 5) & 255, kk = idx >> 13;
    int dy = kk / 7, dx = kk % 7;
    float s = 0.f;
#pragma unroll 8
    for (int m = 0; m < 256; ++m)
        s += w15[co * 768 + m * 3 + dy] * w12[(m * 32 + ci) * 7 + dx];
    Wfb[idx] = __float2bfloat16(s);
}

// w1b[k][c][h][co][j]: bf16 repack of w1 (co,ci,k), ci = c*32+h*8+j.
__global__ void fuse_w1b(const float* __restrict__ w1, __hip_bfloat16* __restrict__ w1b) {
    int idx = blockIdx.x * blockDim.x + threadIdx.x;
    if (idx >= 24576) return;
    int j = idx & 7, co = (idx >> 3) & 31, h = (idx >> 8) & 3, c = (idx >> 10) & 7, k = idx >> 13;
    int ci = c * 32 + h * 8 + j;
    w1b[idx] = __float2bfloat16(w1[(co * 256 + ci) * 3 + k]);
}

// w8b[j][h][co][jj]: bf16 repack of w8 (co,ci,j), ci = h*8+jj.  7*4*32*8 = 7168
__global__ void fuse_w8b(const float* __restrict__ w8, __hip_bfloat16* __restrict__ w8b) {
    int idx = blockIdx.x * blockDim.x + threadIdx.x;
    if (idx >= 7168) return;
    int jj = idx & 7, co = (idx >> 3) & 31, h = (idx >> 8) & 3, j = idx >> 10;
    w8b[idx] = __float2bfloat16(w8[co * 224 + (h * 8 + jj) * 7 + j]);
}

// ---------------- t1 fused MFMA: conv 256->32, 3 w-taps dil 3 ----------------
__global__ __launch_bounds__(256) void k_t1f(const float* __restrict__ x,
                                             const unsigned short* __restrict__ w1b,
                                             float* __restrict__ t1) {
    __shared__ __align__(16) char lds[36864];
    const int t = threadIdx.x, b = blockIdx.x;
    const int n = b / 56, y = b % 56;
    const int w = t >> 6, l = t & 63, h = l >> 4, q = l & 15;
    const float* xr = x + (size_t)(n * 256) * 3136 + y * 56;  // + ci*3136 + xx

    // ---- halo zeros: pos {0,1,2,59..69} x 32 g = 448 units ----
#pragma unroll
    for (int it = 0; it < 2; ++it) {
        int u = it * 256 + t;
        if (u < 448) {
            int pi = u >> 5, g = u & 31;
            int pos = (pi < 3) ? pi : (56 + pi);
            *reinterpret_cast<s8v*>(lds + pos * 512 + ((g ^ (pos & 15)) << 4)) = (s8v)0;
        }
    }
    // ---- coalesced stage: 3584 float4 units (ci, xq) ----
#pragma unroll 2
    for (int it = 0; it < 14; ++it) {
        int u = it * 256 + t;
        int ci = u / 14, xq = u % 14;
        float4 v = *(const float4*)(xr + (size_t)ci * 3136 + xq * 4);
        int g = ci >> 3, lo = (ci & 7) * 2;
#pragma unroll
        for (int j = 0; j < 4; ++j) {
            int pos = xq * 4 + j + 3;
            __hip_bfloat16 bv = __float2bfloat16(((const float*)&v)[j]);
            *(unsigned short*)(lds + pos * 512 + ((g ^ (pos & 15)) << 4) + lo) =
                *(unsigned short*)&bv;
        }
    }
    __syncthreads();

    f32x4 acc[2][4];
#pragma unroll
    for (int m = 0; m < 2; ++m)
#pragma unroll
        for (int nt = 0; nt < 4; ++nt) acc[m][nt] = (f32x4)0.f;

    // ---- K-loop: wave w handles ci-chunks {2w, 2w+1}; no barriers ----
    for (int cc = 0; cc < 2; ++cc) {
        const int c = 2 * w + cc;
        const int g = c * 4 + h;
#pragma unroll
        for (int k = 0; k < 3; ++k) {
            s8v af[2];
#pragma unroll
            for (int m = 0; m < 2; ++m)
                af[m] = *reinterpret_cast<const s8v*>(
                    w1b + (size_t)((((k * 8 + c) * 4 + h) * 32 + m * 16 + q) * 8));
#pragma unroll
            for (int nt = 0; nt < 4; ++nt) {
                int pos = nt * 16 + q + 3 * k;
                s8v bf = *reinterpret_cast<const s8v*>(lds + pos * 512 + ((g ^ (pos & 15)) << 4));
                acc[0][nt] = __builtin_amdgcn_mfma_f32_16x16x32_bf16(af[0], bf, acc[0][nt], 0, 0, 0);
                acc[1][nt] = __builtin_amdgcn_mfma_f32_16x16x32_bf16(af[1], bf, acc[1][nt], 0, 0, 0);
            }
        }
    }

    // ---- reduce 4 partial K-sums via LDS, wave 0 stores ----
    __syncthreads();
    if (w > 0) {
#pragma unroll
        for (int m = 0; m < 2; ++m)
#pragma unroll
            for (int nt = 0; nt < 4; ++nt)
                *reinterpret_cast<f32x4*>(lds + (((w - 1) * 8 + m * 4 + nt) * 64 + l) * 16) =
                    acc[m][nt];
    }
    __syncthreads();
    if (w == 0) {
#pragma unroll
        for (int m = 0; m < 2; ++m)
#pragma unroll
            for (int nt = 0; nt < 4; ++nt) {
                f32x4 a = acc[m][nt];
#pragma unroll
                for (int s = 0; s < 3; ++s)
                    a += *reinterpret_cast<const f32x4*>(
                        lds + ((s * 8 + m * 4 + nt) * 64 + l) * 16);
                int px = nt * 16 + q;
                if (px < 56) {
#pragma unroll
                    for (int r = 0; r < 4; ++r)
                        t1[((size_t)(n * 32 + m * 16 + h * 4 + r) * 56 + y) * 56 + px] = a[r];
                }
            }
    }
}

// ---------------- t4: 32ch, 3x3 taps dil (2,3), via W34 (4 rows/block) ----------------
__global__ __launch_bounds__(256) void k_t4(const float* __restrict__ t1,
                                            const float* __restrict__ W34,
                                            float* __restrict__ t4) {
    int by = blockIdx.x;  // 448
    int n = by / 14;
    int y = (by % 14) * 4 + (threadIdx.x >> 6);
    int px = threadIdx.x & 63;
    if (px >= 56) return;
    float acc = 0.f;
#pragma unroll 4
    for (int ci = 0; ci < 32; ++ci) {
#pragma unroll
        for (int k1 = 0; k1 < 3; ++k1) {
            int yy = y + 2 * k1 - 2;
            if (yy < 0 || yy >= 56) continue;
            const float* r = t1 + ((size_t)(n * 32 + ci) * 56 + yy) * 56;
#pragma unroll
            for (int k2 = 0; k2 < 3; ++k2) {
                int xx = px + 3 * k2 - 3;
                if (xx >= 0 && xx < 56)
                    acc += r[xx] * W34[ci * 9 + k1 * 3 + k2];
            }
        }
    }
    t4[(size_t)(n * 56 + y) * 56 + px] = acc;
}

// ---------------- pool: t4 -> t11 (4 rows/block) ----------------
__global__ __launch_bounds__(256) void k_pool(const float* __restrict__ t4,
                                              float* __restrict__ t11) {
    int by = blockIdx.x;  // 448
    int n = by / 14;
    int y = (by % 14) * 4 + (threadIdx.x >> 6);
    int px = threadIdx.x & 63;
    if (px >= 56) return;
    float s = 0.f;
#pragma unroll
    for (int j = 0; j < 7; ++j) {
        int xx = px + 3 * j - 9;
        bool xin = (xx >= 0 && xx < 56);
#pragma unroll
        for (int dy = -1; dy <= 1; ++dy) {
            int yc = y + dy;
            if (yc < 0 || yc >= 56) continue;
            float m = -3.4e38f;
#pragma unroll
            for (int i = 0; i < 7; ++i) {
                int yy = yc + 3 * i - 9;
                float v = (xin && yy >= 0 && yy < 56) ? t4[(size_t)(n * 56 + yy) * 56 + xx] : 0.f;
                m = fmaxf(m, v);
            }
            s += fmaxf(m, 0.f);
        }
    }
    t11[(size_t)(n * 56 + y) * 56 + px] = s * (1.f / 21.f);
}

// ---------------- t14: 3x3 conv on t11 (4 rows/block) ----------------
__global__ __launch_bounds__(256) void k_t14(const float* __restrict__ t11,
                                             const float* __restrict__ w14,
                                             float* __restrict__ t14) {
    int by = blockIdx.x;  // 448
    int n = by / 14;
    int y = (by % 14) * 4 + (threadIdx.x >> 6);
    int px = threadIdx.x & 63;
    if (px >= 56) return;
    float s = 0.f;
#pragma unroll
    for (int dy = 0; dy < 3; ++dy) {
        int yy = y + dy - 1;
        if (yy < 0 || yy >= 56) continue;
#pragma unroll
        for (int dx = 0; dx < 3; ++dx) {
            int xx = px + dx - 1;
            if (xx < 0 || xx >= 56) continue;
            s += t11[(size_t)(n * 56 + yy) * 56 + xx] * w14[dy * 3 + dx];
        }
    }
    t14[(size_t)(n * 56 + y) * 56 + px] = s;
}

// ---------------- fused t5+t8 MFMA -> t8T ----------------
__global__ __launch_bounds__(256) void k_t58(const float* __restrict__ t1,
                                             const float* __restrict__ p2w,
                                             const float* __restrict__ w5,
                                             const unsigned short* __restrict__ w8b,
                                             char* __restrict__ t8T) {
    __shared__ __align__(16) char lds[4864];  // 76*64
    const int t = threadIdx.x, b = blockIdx.x;
    const int n = b / 56, y = b % 56;
    const int w = t >> 6, l = t & 63, h = l >> 4, q = l & 15;
    const float* t1b = t1 + (size_t)(n * 32) * 3136;

    // halo zeros: pos {0..5, 62..75} x 4 g = 80 units
    if (t < 80) {
        int ph = t >> 2, g = t & 3;
        int pos = (ph < 6) ? ph : (56 + ph);
        *reinterpret_cast<s8v*>(lds + pos * 64 + ((g ^ ((pos >> 1) & 3)) << 4)) = (s8v)0;
    }
    // stage: 448 units (ci, xq); t5 = p2w[ci] * sum_k w5[ci,k] * t1[ci, y+3k-3, :]
#pragma unroll
    for (int it = 0; it < 2; ++it) {
        int u = it * 256 + t;
        if (u < 448) {
            int ci = u / 14, xq = u % 14;
            float sc = p2w[ci];
            float4 s = {0.f, 0.f, 0.f, 0.f};
#pragma unroll
            for (int k = 0; k < 3; ++k) {
                int yy = y + 3 * k - 3;
                if (yy < 0 || yy >= 56) continue;
                float wv = w5[ci * 3 + k] * sc;
                float4 v = *(const float4*)(t1b + (size_t)ci * 3136 + yy * 56 + xq * 4);
                s.x += wv * v.x; s.y += wv * v.y; s.z += wv * v.z; s.w += wv * v.w;
            }
            int g = ci >> 3, lo = (ci & 7) * 2;
#pragma unroll
            for (int j = 0; j < 4; ++j) {
                int pos = xq * 4 + j + 6;
                __hip_bfloat16 bv = __float2bfloat16(((const float*)&s)[j]);
                *(unsigned short*)(lds + pos * 64 + ((g ^ ((pos >> 1) & 3)) << 4) + lo) =
                    *(unsigned short*)&bv;
            }
        }
    }
    __syncthreads();

    f32x4 acc[2];
    acc[0] = (f32x4)0.f; acc[1] = (f32x4)0.f;
#pragma unroll
    for (int j = 0; j < 7; ++j) {
        s8v af[2];
#pragma unroll
        for (int m = 0; m < 2; ++m)
            af[m] = *reinterpret_cast<const s8v*>(
                w8b + (size_t)(((j * 4 + h) * 32 + m * 16 + q) * 8));
        int pos = w * 16 + q + 2 * j;
        s8v bf = *reinterpret_cast<const s8v*>(lds + pos * 64 + ((h ^ ((pos >> 1) & 3)) << 4));
        acc[0] = __builtin_amdgcn_mfma_f32_16x16x32_bf16(af[0], bf, acc[0], 0, 0, 0);
        acc[1] = __builtin_amdgcn_mfma_f32_16x16x32_bf16(af[1], bf, acc[1], 0, 0, 0);
    }

    // store to t8T row (pos = x+3, slot = g ^ ((pos>>1)&3))
    char* rowo = t8T + (size_t)(n * 56 + y) * 4480;
    if (t < 56) {  // halo: pos {0,1,2,59..69} x 4 g
        int ph = t >> 2, g = t & 3;
        int pos = (ph < 3) ? ph : (56 + ph);
        *reinterpret_cast<s8v*>(rowo + pos * 64 + ((g ^ ((pos >> 1) & 3)) << 4)) = (s8v)0;
    }
    int xx = w * 16 + q;
    if (xx < 56) {
        int pos = xx + 3;
#pragma unroll
        for (int m = 0; m < 2; ++m) {
#pragma unroll
            for (int r = 0; r < 4; ++r) {
                int co = m * 16 + h * 4 + r;
                __hip_bfloat16 bv = __float2bfloat16(acc[m][r]);
                *(unsigned short*)(rowo + pos * 64 + (((co >> 3) ^ ((pos >> 1) & 3)) << 4) +
                                   (co & 7) * 2) = *(unsigned short*)&bv;
            }
        }
    }
}

// ---------------- MFMA fused kernel: t8T -> t15 -> t16 + t14 -> out ----------------
// grid 896 (n, y0=2*(b%28)), block 512 = 8 waves. rg = w>>2 row (y0+rg), co0 =
// (w&3)*64. Stage 6 t8T rows (26.9 KB); contiguous kk-range K-loop with 1-deep
// A-fragment register prefetch; shuffle epilogue (t16+t14), coalesced f32 stores.
__global__ __launch_bounds__(512) void k_t15m4(const char* __restrict__ t8T,
                                               const unsigned short* __restrict__ Wfb,
                                               const float* __restrict__ w16,
                                               const float* __restrict__ t14,
                                               float* __restrict__ out) {
    __shared__ __align__(16) char lds[26880];
    const int t = threadIdx.x;
    const int b = blockIdx.x;
    const int n = b / 28, y0 = (b % 28) * 2;
    const int l = t & 63, h = l >> 4, q = l & 15;
    const int w = t >> 6, rg = w >> 2;
    const int y = y0 + rg;
    const int co0 = (w & 3) * 64;

    // ---- stage 6 t8T rows y0-2 .. y0+3 (linear 16B copies) ----
    for (int e = t; e < 1680; e += 512) {
        int ridx = e / 280, u = e - ridx * 280;
        int yy = y0 - 2 + ridx;
        if (yy >= 0 && yy < 56)
            *reinterpret_cast<s8v*>(lds + ridx * 4480 + u * 16) =
                *reinterpret_cast<const s8v*>(t8T + (size_t)(n * 56 + yy) * 4480 + u * 16);
    }
    __syncthreads();

    f32x4 acc[4][4];
#pragma unroll
    for (int m = 0; m < 4; ++m)
#pragma unroll
        for (int nt = 0; nt < 4; ++nt)
            acc[m][nt] = (f32x4)0.f;

    // valid dy are contiguous: kk in [kklo, kkhi)
    const int kklo = (y >= 2) ? 0 : 7;
    const int kkhi = (y <= 53) ? 21 : 14;

    s8v af[4];
#pragma unroll
    for (int m = 0; m < 4; ++m)
        af[m] = *reinterpret_cast<const s8v*>(
            Wfb + (size_t)kklo * 8192 + (co0 + m * 16 + q) * 32 + h * 8);

    for (int kk = kklo; kk < kkhi; ++kk) {
        const int dy = kk / 7, dx = kk - dy * 7;
        const char* bbase = lds + (rg + 2 * dy) * 4480;
        s8v bf[4];
#pragma unroll
        for (int nt = 0; nt < 4; ++nt) {
            int xp = nt * 16 + q + dx;
            bf[nt] = *reinterpret_cast<const s8v*>(bbase + xp * 64 + ((h ^ ((xp >> 1) & 3)) << 4));
        }
        s8v afn[4];
        if (kk + 1 < kkhi) {
#pragma unroll
            for (int m = 0; m < 4; ++m)
                afn[m] = *reinterpret_cast<const s8v*>(
                    Wfb + (size_t)(kk + 1) * 8192 + (co0 + m * 16 + q) * 32 + h * 8);
        }
#pragma unroll
        for (int nt = 0; nt < 4; ++nt)
#pragma unroll
            for (int m = 0; m < 4; ++m)
                acc[m][nt] = __builtin_amdgcn_mfma_f32_16x16x32_bf16(af[m], bf[nt], acc[m][nt], 0, 0, 0);
#pragma unroll
        for (int m = 0; m < 4; ++m) af[m] = afn[m];
    }

    // ---- t16 + t14 epilogue: in-register x+-3 via shuffles, f32, coalesced ----
    const float* t14r = t14 + (size_t)(n * 56 + y) * 56;
    float t14v[4];
#pragma unroll
    for (int nt = 0; nt < 4; ++nt) {
        int xx = nt * 16 + q;
        t14v[nt] = (xx < 56) ? t14r[xx] : 0.f;
    }
    const int srcm = (l & 48) | ((q + 13) & 15);
    const int srcp = (l & 48) | ((q + 3) & 15);
#pragma unroll
    for (int m = 0; m < 4; ++m) {
#pragma unroll
        for (int r = 0; r < 4; ++r) {
            int co = co0 + m * 16 + h * 4 + r;
            float wa = w16[co * 3], wb = w16[co * 3 + 1], wc = w16[co * 3 + 2];
            float v[4], rm[4], rp[4];
#pragma unroll
            for (int nt = 0; nt < 4; ++nt) v[nt] = acc[m][nt][r];
#pragma unroll
            for (int nt = 0; nt < 4; ++nt) {
                rm[nt] = __shfl(v[nt], srcm, 64);
                rp[nt] = __shfl(v[nt], srcp, 64);
            }
            float* orow = out + ((size_t)(n * 256 + co) * 56 + y) * 56;
#pragma unroll
            for (int nt = 0; nt < 4; ++nt) {
                int xx = nt * 16 + q;
                float vm = (q >= 3) ? rm[nt] : (nt > 0 ? rm[nt - 1] : 0.f);
                float vp = (q < 13) ? rp[nt] : (nt < 3 ? rp[nt + 1] : 0.f);
                float s = v[nt] * wb + t14v[nt];
                s += (xx >= 3) ? vm * wa : 0.f;
                s += (xx <= 52) ? vp * wc : 0.f;
                if (xx < 56) orow[xx] = s;
            }
        }
    }
}

extern "C" void kernel_launch(void* const* d_in, const int* in_sizes, int n_in,
                              void* d_out, int out_size, void* d_ws, size_t ws_size,
                              hipStream_t stream) {
    const float* x   = (const float*)d_in[0];
    const float* w1  = (const float*)d_in[1];
    const float* p2w = (const float*)d_in[2];
    const float* w3  = (const float*)d_in[3];
    const float* w4  = (const float*)d_in[4];
    const float* w5  = (const float*)d_in[5];
    const float* w8  = (const float*)d_in[6];
    const float* w12 = (const float*)d_in[7];
    const float* w14 = (const float*)d_in[8];
    const float* w15 = (const float*)d_in[9];
    const float* w16 = (const float*)d_in[10];
    float* out = (float*)d_out;

    float* ws = (float*)d_ws;
    float* t1   = ws;                  // 3211264 f32
    char*  t8T  = (char*)(t1 + 3211264);  // 8,028,160 B
    float* t4   = t1 + 2 * 3211264;    // 100352
    float* t11  = t4 + 100352;         // 100352
    float* t14v = t11 + 100352;        // 100352
    float* W34  = t14v + 100352;       // 288
    __hip_bfloat16* Wfb = (__hip_bfloat16*)(W34 + 288);   // 172032 bf16
    __hip_bfloat16* w1b = Wfb + 172032;                   // 24576 bf16
    __hip_bfloat16* w8b = w1b + 24576;                    // 7168 bf16

    fuse_w34<<<5, 64, 0, stream>>>(w3, w4, W34);
    fuse_w1215b<<<672, 256, 0, stream>>>(w15, w12, Wfb);
    fuse_w1b<<<96, 256, 0, stream>>>(w1, w1b);
    fuse_w8b<<<28, 256, 0, stream>>>(w8, w8b);

    k_t1f<<<1792, 256, 0, stream>>>(x, (const unsigned short*)w1b, t1);
    k_t4<<<448, 256, 0, stream>>>(t1, W34, t4);
    k_pool<<<448, 256, 0, stream>>>(t4, t11);
    k_t14<<<448, 256, 0, stream>>>(t11, w14, t14v);
    k_t58<<<1792, 256, 0, stream>>>(t1, p2w, w5, (const unsigned short*)w8b, t8T);
    k_t15m4<<<896, 512, 0, stream>>>(t8T, (const unsigned short*)Wfb, w16, t14v, out);
}